// Round 2
// 483.097 us; speedup vs baseline: 1.4394x; 1.4394x over previous
//
#include <hip/hip_runtime.h>
#include <stdint.h>

#define NB 128
#define NC 512
#define NH 10
#define NW 20
#define NP 200      // NH*NW
#define ND3 1323
#define NDP 448     // per-pair padded channel row (441 -> 448, 896B aligned)
#define MROWS 25600 // NB*NP flattened GEMM rows per tensor
#define KCORR 1344  // 3*448 K extent for corr conv-GEMM
#define KCAT  1536  // 3*512

typedef unsigned short u16;
typedef unsigned int u32;

typedef short bh8 __attribute__((ext_vector_type(8)));   // 8 bf16 (4 VGPRs)
typedef float f4 __attribute__((ext_vector_type(4)));    // 4 fp32 acc

// ---- workspace layout (bytes) ----
// fa occupies [0, 78.6MB); dead after k_conv1x1_mfma. corr + Ucorr/Ucat alias it.
#define OFF_FA     0ULL
#define SZ_FA      (3ULL*MROWS*NC*2)             // 78,643,200
#define OFF_CORR   0ULL
#define SZ_CORR    (3ULL*NB*NP*NDP*2)            // 68,812,800  [b][pair][p][448]
#define OFF_UCORR  (OFF_CORR + SZ_CORR + 256)
#define SZ_U       (1ULL*MROWS*32*4)             // 3,276,800
#define OFF_UCAT   (OFF_UCORR + SZ_U)            // ends ~75.4MB < 78.6MB
#define OFF_FT     (OFF_FA + SZ_FA)
#define SZ_FT      (3ULL*MROWS*NC*2 + 65536)     // +64 pad rows for over-read
#define OFF_WBF    (OFF_FT + SZ_FT)
#define SZ_WBF     (3ULL*NC*NC*2)
#define OFF_WCTB   (OFF_WBF + SZ_WBF)
#define SZ_WCTB    (32ULL*KCORR*2)               // bf16 [32][1344]
#define OFF_WCATB  (OFF_WCTB + SZ_WCTB)
#define SZ_WCATB   (32ULL*KCAT*2)                // bf16 [32][1536]

__device__ __forceinline__ float bf2f(u16 a) {
    return __uint_as_float(((u32)a) << 16);
}
__device__ __forceinline__ u16 f2bf(float x) {
    u32 u = __float_as_uint(x);
    return (u16)((u + 0x7fffu + ((u >> 16) & 1u)) >> 16);
}

// direct global->LDS DMA, 16B per lane. lds dest must be wave-uniform base;
// HW scatters lane l to base + l*16.
__device__ __forceinline__ void gload16(const void* g, void* l) {
    __builtin_amdgcn_global_load_lds(
        (const __attribute__((address_space(1))) void*)g,
        (__attribute__((address_space(3))) void*)l, 16, 0, 0);
}

// ---- prep: build bf16 weight matrices ----
__global__ __launch_bounds__(256) void k_prep(const float* __restrict__ Wcorr,
                                              const float* __restrict__ Wcat,
                                              const float* __restrict__ Wa,
                                              const float* __restrict__ Wb,
                                              const float* __restrict__ Wc,
                                              u16* __restrict__ wctb,
                                              u16* __restrict__ wcatb,
                                              u16* __restrict__ wbf) {
    int idx = blockIdx.x * 256 + threadIdx.x;
    const int n1 = 32 * KCORR;     // 43008
    const int n2 = 32 * KCAT;      // 49152
    const int n3 = 3 * NC * NC;    // 786432
    if (idx < n1) {
        int k = idx % KCORR;
        int n = idx / KCORR;
        int pair = k / NDP, ch = k - pair * NDP;
        float v = 0.0f;
        if (n < 27 && ch < 441) {
            int d = pair * 441 + ch;
            int tap = n / 3, o = n % 3;
            int ky = tap / 3, kx = tap % 3;
            v = Wcorr[((o * ND3 + d) * 3 + ky) * 3 + kx];
        }
        wctb[idx] = f2bf(v);
    } else if (idx < n1 + n2) {
        int j = idx - n1;
        int i = j % KCAT;
        int n = j / KCAT;
        float v = 0.0f;
        if (n < 27) {
            int tap = n / 3, o = n % 3;
            int ky = tap / 3, kx = tap % 3;
            v = Wcat[((o * 1536 + i) * 3 + ky) * 3 + kx];
        }
        wcatb[j] = f2bf(v);
    } else if (idx < n1 + n2 + n3) {
        int j = idx - n1 - n2;
        int t = j >> 18;
        const float* W = (t == 0) ? Wa : (t == 1) ? Wb : Wc;
        wbf[j] = f2bf(W[j & 262143]);
    }
}

// ---- transpose feat [t][b][c][p] f32 -> fa [t][(b,p)][c] bf16 ----
__global__ __launch_bounds__(256) void k_fa(const float* __restrict__ feat1,
                                            const float* __restrict__ feat2,
                                            const float* __restrict__ feat3,
                                            u16* __restrict__ fa) {
    const int tid = threadIdx.x;
    const int ct = blockIdx.x;
    const int t = blockIdx.y >> 7, b = blockIdx.y & 127;
    const float* feat = (t == 0) ? feat1 : (t == 1) ? feat2 : feat3;

    __shared__ u16 Ls[NP * 72];

    const int cl = tid >> 2;
    const int pc = tid & 3;
    const float* src = feat + ((size_t)b * NC + ct * 64 + cl) * NP + pc * 50;
#pragma unroll
    for (int u = 0; u < 50; u += 2) {
        float2 v = *(const float2*)(src + u);
        int p = pc * 50 + u;
        Ls[p * 72 + cl] = f2bf(v.x);
        Ls[(p + 1) * 72 + cl] = f2bf(v.y);
    }
    __syncthreads();
    for (int idx = tid; idx < 1600; idx += 256) {
        int p = idx >> 3, ck = idx & 7;
        uint4 v = *(const uint4*)&Ls[p * 72 + ck * 8];
        *(uint4*)&fa[((size_t)t * MROWS + b * NP + p) * NC + ct * 64 + ck * 8] = v;
    }
}

// ---- 1x1 conv as MFMA GEMM, XCD-aware 1D grid ----
// 2400 blocks; xcd = bid&7, local = bid>>3 in [0,300):
// mb = xcd*25 + local/12 (A-tile pinned to one XCD), (nb,t) = local%12.
// K-loop: 2-phase double-buffered global_load_lds (16B/lane DMA):
//   STAGE(next buf) issued EARLY -> ds_read+MFMA current buf -> __syncthreads
// __syncthreads' vmcnt(0)+lgkmcnt(0) drain is count-robust (no hand-counted
// waits -> no race), and the DMA latency hides under the MFMA phase.
// LDS tiles are linear [row][64] bf16 with 16B-chunk XOR swizzle:
// LDS[row][c] holds global chunk c ^ (row&7)  (both-sides involution).
__global__ __launch_bounds__(256) void k_conv1x1_mfma(
    const u16* __restrict__ fa, const u16* __restrict__ wbf,
    const float* __restrict__ ba, const float* __restrict__ bb,
    const float* __restrict__ bc, u16* __restrict__ fT) {
    const int tid = threadIdx.x;
    const int bid = blockIdx.x;
    const int xcd = bid & 7, local = bid >> 3;
    const int mb = xcd * 25 + local / 12;
    const int nbt = local % 12;
    const int nb = nbt & 3;
    const int t = nbt >> 2;
    const float* bias = (t == 0) ? ba : (t == 1) ? bb : bc;

    // A bufs: [2][128][64] at 0; B bufs: [2][128][64] at 16384 (u16 units).
    __shared__ __align__(16) u16 smem[4 * 128 * 64];   // 65,536 B

    const u16* Ag = fa + (size_t)t * MROWS * NC + (size_t)mb * 128 * NC;
    const u16* Bg = wbf + (size_t)t * NC * NC + (size_t)nb * 128 * NC;

    const int lane = tid & 63;
    const int wave = tid >> 6;
    const int wm = (wave & 1) * 64;
    const int wn = (wave >> 1) * 64;
    const int quad = lane >> 4;
    const int ln16 = lane & 15;

    const int r0 = lane >> 3;            // row within 8-row DMA chunk
    const int csrc = (lane & 7) ^ r0;    // pre-swizzled source 16B chunk

    f4 acc[4][4];
    const f4 zz = {0.f, 0.f, 0.f, 0.f};
#pragma unroll
    for (int i = 0; i < 4; ++i)
#pragma unroll
        for (int j = 0; j < 4; ++j) acc[i][j] = zz;

    // per wave per k-step: 4 A-chunks + 4 B-chunks = 8 DMA loads (1KB each)
#define STAGE1(buf, ks) do {                                                   \
        int _ko = (ks) * 64 + csrc * 8;                                        \
        _Pragma("unroll")                                                      \
        for (int _i = 0; _i < 4; ++_i) {                                       \
            int _ra = wave * 32 + _i * 8;                                      \
            gload16(Ag + (size_t)(_ra + r0) * NC + _ko,                        \
                    &smem[(buf) * 8192 + _ra * 64]);                           \
            gload16(Bg + (size_t)(_ra + r0) * NC + _ko,                        \
                    &smem[16384 + (buf) * 8192 + _ra * 64]);                   \
        }                                                                      \
    } while (0)

    STAGE1(0, 0);
    __syncthreads();   // drain buf0 DMAs; barrier
#pragma unroll
    for (int ks = 0; ks < 8; ++ks) {
        // issue next-tile DMAs early: latency hides under this tile's MFMAs.
        // overwrite of buf[(ks&1)^1] is safe: its readers drained at the
        // __syncthreads that ended iteration ks-1.
        if (ks < 7) STAGE1((ks & 1) ^ 1, ks + 1);
        const u16* Ab = &smem[(ks & 1) * 8192];
        const u16* Bb = &smem[16384 + (ks & 1) * 8192];
#pragma unroll
        for (int h = 0; h < 2; ++h) {
            bh8 afr[4], bfr[4];
#pragma unroll
            for (int s = 0; s < 4; ++s) {
                int cw = ((h * 4 + quad) ^ (ln16 & 7)) * 8;
                afr[s] = *(const bh8*)&Ab[(wm + s * 16 + ln16) * 64 + cw];
                bfr[s] = *(const bh8*)&Bb[(wn + s * 16 + ln16) * 64 + cw];
            }
#pragma unroll
            for (int i = 0; i < 4; ++i)
#pragma unroll
                for (int j = 0; j < 4; ++j)
                    acc[i][j] = __builtin_amdgcn_mfma_f32_16x16x32_bf16(
                        afr[i], bfr[j], acc[i][j], 0, 0, 0);
        }
        __syncthreads();   // drains this iter's DMAs (vmcnt 0) + barrier
    }
#undef STAGE1

    // epilogue: bias + bf16 pack into LDS tile [128][136], coalesced stores
#pragma unroll
    for (int j = 0; j < 4; ++j) {
        int tcol = wn + j * 16 + ln16;
        float bi = bias[nb * 128 + tcol];
#pragma unroll
        for (int i = 0; i < 4; ++i) {
            int trow = wm + i * 16 + quad * 4;
#pragma unroll
            for (int r = 0; r < 4; ++r)
                smem[(trow + r) * 136 + tcol] = f2bf(acc[i][j][r] + bi);
        }
    }
    __syncthreads();
    const size_t obase = ((size_t)t * MROWS + (size_t)mb * 128) * NC + nb * 128;
#pragma unroll
    for (int it = 0; it < 8; ++it) {
        int idx = tid + 256 * it;
        int row = idx >> 4, ck = idx & 15;
        *(uint4*)(fT + obase + (size_t)row * NC + ck * 8) =
            *(const uint4*)&smem[row * 136 + ck * 8];
    }
}

// ---- Gram via MFMA; XCD-aware 1D grid; full 448-wide rows assembled in LDS ----
// 1536 blocks; same 2-phase double-buffered DMA structure as conv1x1.
// A tile 64x64 (2 DMA/wave), B tile 256x64 (8 DMA/wave).
__global__ __launch_bounds__(256) void k_gram_mfma(const u16* __restrict__ fT,
                                                   u16* __restrict__ corr) {
    const int tid = threadIdx.x;
    const int bid = blockIdx.x;
    const int xcd = bid & 7, local = bid >> 3;
    const int gidx = xcd * 48 + (local >> 2);
    const int mt = local & 3;
    const int b = gidx / 3, pair = gidx % 3;
    const int tA = (pair == 2) ? 1 : 0;
    const int tB = (pair == 0) ? 1 : 2;

    // A bufs: [2][64][64] at 0 (4096 u16 each); B bufs: [2][256][64] at 8192.
    __shared__ __align__(16) u16 smem[2 * 64 * 64 + 2 * 256 * 64];  // 81,920 B

    const u16* Ag = fT + ((size_t)tA * NB + b) * NP * NC + (size_t)mt * 64 * NC;
    const u16* Bg = fT + ((size_t)tB * NB + b) * NP * NC;

    const int lane = tid & 63;
    const int wave = tid >> 6;
    const int wn = wave * 64;
    const int quad = lane >> 4;
    const int ln16 = lane & 15;

    const int r0 = lane >> 3;
    const int csrc = (lane & 7) ^ r0;

    f4 acc[4][4];
    const f4 zz = {0.f, 0.f, 0.f, 0.f};
#pragma unroll
    for (int i = 0; i < 4; ++i)
#pragma unroll
        for (int j = 0; j < 4; ++j) acc[i][j] = zz;

#define STAGE2(buf, ks) do {                                                   \
        int _ko = (ks) * 64 + csrc * 8;                                        \
        _Pragma("unroll")                                                      \
        for (int _i = 0; _i < 2; ++_i) {                                       \
            int _ra = wave * 16 + _i * 8;                                      \
            gload16(Ag + (size_t)(_ra + r0) * NC + _ko,                        \
                    &smem[(buf) * 4096 + _ra * 64]);                           \
        }                                                                      \
        _Pragma("unroll")                                                      \
        for (int _i = 0; _i < 8; ++_i) {                                       \
            int _rb = wave * 64 + _i * 8;                                      \
            gload16(Bg + (size_t)(_rb + r0) * NC + _ko,                        \
                    &smem[8192 + (buf) * 16384 + _rb * 64]);                   \
        }                                                                      \
    } while (0)

    STAGE2(0, 0);
    __syncthreads();
#pragma unroll
    for (int ks = 0; ks < 8; ++ks) {
        if (ks < 7) STAGE2((ks & 1) ^ 1, ks + 1);
        const u16* Ab = &smem[(ks & 1) * 4096];
        const u16* Bb = &smem[8192 + (ks & 1) * 16384];
#pragma unroll
        for (int h = 0; h < 2; ++h) {
            bh8 afr[4], bfr[4];
#pragma unroll
            for (int s = 0; s < 4; ++s) {
                int cw = ((h * 4 + quad) ^ (ln16 & 7)) * 8;
                afr[s] = *(const bh8*)&Ab[(s * 16 + ln16) * 64 + cw];
                bfr[s] = *(const bh8*)&Bb[(wn + s * 16 + ln16) * 64 + cw];
            }
#pragma unroll
            for (int i = 0; i < 4; ++i)
#pragma unroll
                for (int j = 0; j < 4; ++j)
                    acc[i][j] = __builtin_amdgcn_mfma_f32_16x16x32_bf16(
                        afr[i], bfr[j], acc[i][j], 0, 0, 0);
        }
        __syncthreads();
    }
#undef STAGE2

    // epilogue: zero LDS rows, scatter valid (p1,ch), write contiguous rows
    {
        const uint4 z4 = make_uint4(0, 0, 0, 0);
#pragma unroll
        for (int it = 0; it < 14; ++it)
            ((uint4*)smem)[tid + 256 * it] = z4;
    }
    __syncthreads();
#pragma unroll
    for (int i = 0; i < 4; ++i) {
#pragma unroll
        for (int r = 0; r < 4; ++r) {
            int p1l = i * 16 + quad * 4 + r;
            int p1 = mt * 64 + p1l;
            if (p1 >= NP) continue;
            int y1 = p1 / 20, x1 = p1 - y1 * 20;
#pragma unroll
            for (int j = 0; j < 4; ++j) {
                int p2 = wn + j * 16 + ln16;
                if (p2 >= NP) continue;
                int y2 = p2 / 20, x2 = p2 - y2 * 20;
                int oy = y2 - y1, ox = x2 - x1;
                if (((oy | ox) & 1) == 0) {
                    int ch = ((oy + 20) >> 1) * 21 + ((ox + 20) >> 1);
                    float v = acc[i][j][r] * (1.0f / 512.0f);
                    v = (v > 0.0f) ? v : 0.1f * v;
                    smem[p1l * NDP + ch] = f2bf(v);
                }
            }
        }
    }
    __syncthreads();
    u16* Crow = corr + ((size_t)(b * 3 + pair)) * NP * NDP;
#pragma unroll
    for (int it = 0; it < 14; ++it) {
        int idx = tid + 256 * it;          // 64 rows * 56 uint4
        int row = idx / 56, cq = idx - row * 56;
        int p1 = mt * 64 + row;
        if (p1 < NP)
            *(uint4*)(Crow + (size_t)p1 * NDP + cq * 8) =
                *(const uint4*)&smem[row * NDP + cq * 8];
    }
}

#define LDA 72
// ---- both conv-GEMMs in one dispatch: grid (200, 2), y = mode ----
// mode 0: A = corr [b][pair][p][448], k = pair*448+ch, 21 k-iters
// mode 1: A = fT (3 stacked [25600][512]), k = t*512+c, 24 k-iters
__global__ __launch_bounds__(256) void k_convgemm(const u16* __restrict__ corr,
                                                  const u16* __restrict__ fT,
                                                  const u16* __restrict__ wctb,
                                                  const u16* __restrict__ wcatb,
                                                  float* __restrict__ Ucorr,
                                                  float* __restrict__ Ucat) {
    const int tid = threadIdx.x;
    const int mb = blockIdx.x;
    const int mode = blockIdx.y;
    const u16* A0 = mode ? fT : corr;
    const u16* Bn = mode ? wcatb : wctb;
    float* U = mode ? Ucat : Ucorr;
    const int kiters = mode ? (KCAT / 64) : (KCORR / 64);
    const int Kpad = kiters * 64;

    __shared__ __align__(16) u16 As[128 * LDA];
    __shared__ __align__(16) u16 Bs[32 * LDA];

    const int lane = tid & 63;
    const int wave = tid >> 6;
    const int wm = wave * 32;
    const int quad = lane >> 4;
    const int ln16 = lane & 15;

    size_t abase[4];
    int ack[4];
#pragma unroll
    for (int i = 0; i < 4; ++i) {
        int idx = tid + 256 * i;
        int r = idx >> 3;
        ack[i] = (idx & 7) * 8;
        int m = mb * 128 + r;
        if (mode == 0) {
            int b = m / NP, p = m - b * NP;
            abase[i] = ((size_t)(b * 3) * NP + p) * NDP;
        } else {
            abase[i] = (size_t)m * NC;
        }
    }

    f4 acc00 = {0,0,0,0}, acc01 = {0,0,0,0}, acc10 = {0,0,0,0}, acc11 = {0,0,0,0};

    uint4 ga[4], gb1;
#pragma unroll
    for (int i = 0; i < 4; ++i) {
        int k = ack[i];
        const u16* ap = (mode == 0)
            ? (A0 + abase[i] + (size_t)(k / NDP) * (NP * NDP) + (k % NDP))
            : (A0 + (size_t)(k >> 9) * MROWS * NC + abase[i] + (k & 511));
        ga[i] = *(const uint4*)ap;
    }
    {
        int r = tid >> 3, ck = tid & 7;
        gb1 = *(const uint4*)(Bn + (size_t)r * Kpad + ck * 8);
    }
    for (int ks = 0; ks < kiters; ++ks) {
        __syncthreads();
#pragma unroll
        for (int i = 0; i < 4; ++i) {
            int idx = tid + 256 * i;
            int r = idx >> 3, ck = idx & 7;
            *(uint4*)&As[r * LDA + ck * 8] = ga[i];
        }
        {
            int r = tid >> 3, ck = tid & 7;
            *(uint4*)&Bs[r * LDA + ck * 8] = gb1;
        }
        __syncthreads();
        if (ks < kiters - 1) {
            int kof = (ks + 1) * 64;
#pragma unroll
            for (int i = 0; i < 4; ++i) {
                int k = kof + ack[i];
                const u16* ap = (mode == 0)
                    ? (A0 + abase[i] + (size_t)(k / NDP) * (NP * NDP) + (k % NDP))
                    : (A0 + (size_t)(k >> 9) * MROWS * NC + abase[i] + (k & 511));
                ga[i] = *(const uint4*)ap;
            }
            int r = tid >> 3, ck = tid & 7;
            gb1 = *(const uint4*)(Bn + (size_t)r * Kpad + kof + ck * 8);
        }
#pragma unroll
        for (int h = 0; h < 2; ++h) {
            bh8 a0 = *(const bh8*)&As[(wm + ln16) * LDA + h * 32 + quad * 8];
            bh8 a1 = *(const bh8*)&As[(wm + 16 + ln16) * LDA + h * 32 + quad * 8];
            bh8 b0 = *(const bh8*)&Bs[(ln16) * LDA + h * 32 + quad * 8];
            bh8 b1 = *(const bh8*)&Bs[(16 + ln16) * LDA + h * 32 + quad * 8];
            acc00 = __builtin_amdgcn_mfma_f32_16x16x32_bf16(a0, b0, acc00, 0, 0, 0);
            acc01 = __builtin_amdgcn_mfma_f32_16x16x32_bf16(a0, b1, acc01, 0, 0, 0);
            acc10 = __builtin_amdgcn_mfma_f32_16x16x32_bf16(a1, b0, acc10, 0, 0, 0);
            acc11 = __builtin_amdgcn_mfma_f32_16x16x32_bf16(a1, b1, acc11, 0, 0, 0);
        }
    }
    const int rbase = mb * 128 + wm + quad * 4;
#pragma unroll
    for (int r = 0; r < 4; ++r) {
        U[(size_t)(rbase + r) * 32 + ln16] = acc00[r];
        U[(size_t)(rbase + r) * 32 + 16 + ln16] = acc01[r];
        U[(size_t)(rbase + 16 + r) * 32 + ln16] = acc10[r];
        U[(size_t)(rbase + 16 + r) * 32 + 16 + ln16] = acc11[r];
    }
}

// ---- merged tail: 9-neighbor gather + bias/relu + both MLPs + final linear ----
__global__ __launch_bounds__(256) void k_tail(
    const float* __restrict__ Ucorr, const float* __restrict__ Ucat,
    const float* __restrict__ bcorr, const float* __restrict__ bcat,
    const float* __restrict__ cf_w1, const float* __restrict__ cf_b1,
    const float* __restrict__ cf_w2, const float* __restrict__ cf_b2,
    const float* __restrict__ ccf_w1, const float* __restrict__ ccf_b1,
    const float* __restrict__ ccf_w2, const float* __restrict__ ccf_b2,
    const float* __restrict__ Wout, const float* __restrict__ bout,
    float* __restrict__ out) {
    const int tid = threadIdx.x;
    const int b = blockIdx.x;
    __shared__ float Lc[NP][28];
    __shared__ float La[NP][28];
    __shared__ float cv[600], vv[600], h1[256], h2a[128], h2b[128];
    for (int idx = tid; idx < NP * 27; idx += 256) {
        int p = idx / 27, n = idx - p * 27;
        Lc[p][n] = Ucorr[(size_t)(b * NP + p) * 32 + n];
        La[p][n] = Ucat[(size_t)(b * NP + p) * 32 + n];
    }
    __syncthreads();
    for (int idx = tid; idx < 1200; idx += 256) {
        int path = idx / 600;
        int rem = idx - path * 600;
        int o = rem / 200, p = rem - o * 200;
        int y = p / 20, x = p - y * 20;
        float s = (path == 0) ? bcorr[o] : bcat[o];
        for (int ky = 0; ky < 3; ++ky) {
            int yy = y + ky - 1;
            if (yy < 0 || yy >= NH) continue;
            for (int kx = 0; kx < 3; ++kx) {
                int xx = x + kx - 1;
                if (xx < 0 || xx >= NW) continue;
                int n = (ky * 3 + kx) * 3 + o;
                s += (path == 0) ? Lc[yy * 20 + xx][n] : La[yy * 20 + xx][n];
            }
        }
        if (path == 0) cv[rem] = fmaxf(s, 0.0f);
        else           vv[rem] = s;
    }
    __syncthreads();
    {
        float s = cf_b1[tid];
        const float* wr = cf_w1 + (size_t)tid * 600;
        for (int k = 0; k < 600; k += 4) {
            float4 wv = *(const float4*)&wr[k];
            s = fmaf(cv[k], wv.x, s); s = fmaf(cv[k + 1], wv.y, s);
            s = fmaf(cv[k + 2], wv.z, s); s = fmaf(cv[k + 3], wv.w, s);
        }
        h1[tid] = fmaxf(s, 0.0f);
    }
    __syncthreads();
    if (tid < 128) {
        float s = cf_b2[tid];
        const float* wr = cf_w2 + (size_t)tid * 256;
        for (int k = 0; k < 256; k += 4) {
            float4 wv = *(const float4*)&wr[k];
            s = fmaf(h1[k], wv.x, s); s = fmaf(h1[k + 1], wv.y, s);
            s = fmaf(h1[k + 2], wv.z, s); s = fmaf(h1[k + 3], wv.w, s);
        }
        h2a[tid] = fmaxf(s, 0.0f);
    }
    __syncthreads();
    {
        float s = ccf_b1[tid];
        const float* wr = ccf_w1 + (size_t)tid * 600;
        for (int k = 0; k < 600; k += 4) {
            float4 wv = *(const float4*)&wr[k];
            s = fmaf(vv[k], wv.x, s); s = fmaf(vv[k + 1], wv.y, s);
            s = fmaf(vv[k + 2], wv.z, s); s = fmaf(vv[k + 3], wv.w, s);
        }
        h1[tid] = fmaxf(s, 0.0f);
    }
    __syncthreads();
    if (tid < 128) {
        float s = ccf_b2[tid];
        const float* wr = ccf_w2 + (size_t)tid * 256;
        for (int k = 0; k < 256; k += 4) {
            float4 wv = *(const float4*)&wr[k];
            s = fmaf(h1[k], wv.x, s); s = fmaf(h1[k + 1], wv.y, s);
            s = fmaf(h1[k + 2], wv.z, s); s = fmaf(h1[k + 3], wv.w, s);
        }
        h2b[tid] = fmaxf(s, 0.0f);
    }
    __syncthreads();
    if (tid < 2) {
        float s = bout[tid];
        const float* wr = Wout + (size_t)tid * 256;
        for (int k = 0; k < 128; ++k) {
            s = fmaf(h2a[k], wr[k], s);
            s = fmaf(h2b[k], wr[128 + k], s);
        }
        out[(size_t)b * 2 + tid] = s;
    }
}

extern "C" void kernel_launch(void* const* d_in, const int* in_sizes, int n_in,
                              void* d_out, int out_size, void* d_ws, size_t ws_size,
                              hipStream_t stream) {
    const float* feat1  = (const float*)d_in[0];
    const float* feat2  = (const float*)d_in[1];
    const float* feat3  = (const float*)d_in[2];
    const float* Wa     = (const float*)d_in[3];
    const float* ba     = (const float*)d_in[4];
    const float* Wb     = (const float*)d_in[5];
    const float* bb     = (const float*)d_in[6];
    const float* Wc     = (const float*)d_in[7];
    const float* bc     = (const float*)d_in[8];
    const float* Wcorr  = (const float*)d_in[9];
    const float* bcorr  = (const float*)d_in[10];
    const float* Wcat   = (const float*)d_in[11];
    const float* bcat   = (const float*)d_in[12];
    const float* cf_w1  = (const float*)d_in[13];
    const float* cf_b1  = (const float*)d_in[14];
    const float* cf_w2  = (const float*)d_in[15];
    const float* cf_b2  = (const float*)d_in[16];
    const float* ccf_w1 = (const float*)d_in[17];
    const float* ccf_b1 = (const float*)d_in[18];
    const float* ccf_w2 = (const float*)d_in[19];
    const float* ccf_b2 = (const float*)d_in[20];
    const float* Wout   = (const float*)d_in[21];
    const float* bout   = (const float*)d_in[22];

    char* ws = (char*)d_ws;
    u16*  fa    = (u16*)(ws + OFF_FA);
    u16*  corr  = (u16*)(ws + OFF_CORR);     // aliases fa (disjoint lifetimes)
    float* Ucorr = (float*)(ws + OFF_UCORR);  // aliases fa tail
    float* Ucat  = (float*)(ws + OFF_UCAT);
    u16*  fT    = (u16*)(ws + OFF_FT);
    u16*  wbf   = (u16*)(ws + OFF_WBF);
    u16*  wctb  = (u16*)(ws + OFF_WCTB);
    u16*  wcatb = (u16*)(ws + OFF_WCATB);

    k_prep<<<3432, 256, 0, stream>>>(Wcorr, Wcat, Wa, Wb, Wc, wctb, wcatb, wbf);
    k_fa<<<dim3(8, 384), 256, 0, stream>>>(feat1, feat2, feat3, fa);
    k_conv1x1_mfma<<<2400, 256, 0, stream>>>(fa, wbf, ba, bb, bc, fT);
    // fa dead from here; gram writes every byte of corr (no memset needed)
    k_gram_mfma<<<1536, 256, 0, stream>>>(fT, corr);
    k_convgemm<<<dim3(200, 2), 256, 0, stream>>>(corr, fT, wctb, wcatb, Ucorr, Ucat);
    k_tail<<<128, 256, 0, stream>>>(Ucorr, Ucat, bcorr, bcat,
                                    cf_w1, cf_b1, cf_w2, cf_b2,
                                    ccf_w1, ccf_b1, ccf_w2, ccf_b2, Wout, bout,
                                    (float*)d_out);
}

// Round 3
// 451.349 us; speedup vs baseline: 1.5407x; 1.0703x over previous
//
#include <hip/hip_runtime.h>
#include <stdint.h>

#define NB 128
#define NC 512
#define NH 10
#define NW 20
#define NP 200      // NH*NW
#define ND3 1323
#define NDP 448     // per-pair padded channel row (441 -> 448, 896B aligned)
#define MROWS 25600 // NB*NP flattened GEMM rows per tensor
#define KCORR 1344  // 3*448 K extent for corr conv-GEMM
#define KCAT  1536  // 3*512

typedef unsigned short u16;
typedef unsigned int u32;

typedef short bh8 __attribute__((ext_vector_type(8)));   // 8 bf16 (4 VGPRs)
typedef float f4 __attribute__((ext_vector_type(4)));    // 4 fp32 acc

// ---- workspace layout (bytes) ----
// fa occupies [0, 78.6MB); dead after k_conv1x1_mfma. corr + Ucorr/Ucat alias it.
#define OFF_FA     0ULL
#define SZ_FA      (3ULL*MROWS*NC*2)             // 78,643,200
#define OFF_CORR   0ULL
#define SZ_CORR    (3ULL*NB*NP*NDP*2)            // 68,812,800  [b][pair][p][448]
#define OFF_UCORR  (OFF_CORR + SZ_CORR + 256)
#define SZ_U       (1ULL*MROWS*32*4)             // 3,276,800
#define OFF_UCAT   (OFF_UCORR + SZ_U)            // ends ~75.4MB < 78.6MB
#define OFF_FT     (OFF_FA + SZ_FA)
#define SZ_FT      (3ULL*MROWS*NC*2 + 65536)     // +64 pad rows for over-read
#define OFF_WBF    (OFF_FT + SZ_FT)
#define SZ_WBF     (3ULL*NC*NC*2)
#define OFF_WCTB   (OFF_WBF + SZ_WBF)
#define SZ_WCTB    (32ULL*KCORR*2)               // bf16 [32][1344]
#define OFF_WCATB  (OFF_WCTB + SZ_WCTB)
#define SZ_WCATB   (32ULL*KCAT*2)                // bf16 [32][1536]

__device__ __forceinline__ float bf2f(u16 a) {
    return __uint_as_float(((u32)a) << 16);
}
__device__ __forceinline__ u16 f2bf(float x) {
    u32 u = __float_as_uint(x);
    return (u16)((u + 0x7fffu + ((u >> 16) & 1u)) >> 16);
}

// direct global->LDS DMA, 16B per lane. lds dest must be wave-uniform base;
// HW scatters lane l to base + l*16.
__device__ __forceinline__ void gload16(const void* g, void* l) {
    __builtin_amdgcn_global_load_lds(
        (const __attribute__((address_space(1))) void*)g,
        (__attribute__((address_space(3))) void*)l, 16, 0, 0);
}

// ---- prep: build bf16 weight matrices ----
__global__ __launch_bounds__(256) void k_prep(const float* __restrict__ Wcorr,
                                              const float* __restrict__ Wcat,
                                              const float* __restrict__ Wa,
                                              const float* __restrict__ Wb,
                                              const float* __restrict__ Wc,
                                              u16* __restrict__ wctb,
                                              u16* __restrict__ wcatb,
                                              u16* __restrict__ wbf) {
    int idx = blockIdx.x * 256 + threadIdx.x;
    const int n1 = 32 * KCORR;     // 43008
    const int n2 = 32 * KCAT;      // 49152
    const int n3 = 3 * NC * NC;    // 786432
    if (idx < n1) {
        int k = idx % KCORR;
        int n = idx / KCORR;
        int pair = k / NDP, ch = k - pair * NDP;
        float v = 0.0f;
        if (n < 27 && ch < 441) {
            int d = pair * 441 + ch;
            int tap = n / 3, o = n % 3;
            int ky = tap / 3, kx = tap % 3;
            v = Wcorr[((o * ND3 + d) * 3 + ky) * 3 + kx];
        }
        wctb[idx] = f2bf(v);
    } else if (idx < n1 + n2) {
        int j = idx - n1;
        int i = j % KCAT;
        int n = j / KCAT;
        float v = 0.0f;
        if (n < 27) {
            int tap = n / 3, o = n % 3;
            int ky = tap / 3, kx = tap % 3;
            v = Wcat[((o * 1536 + i) * 3 + ky) * 3 + kx];
        }
        wcatb[j] = f2bf(v);
    } else if (idx < n1 + n2 + n3) {
        int j = idx - n1 - n2;
        int t = j >> 18;
        const float* W = (t == 0) ? Wa : (t == 1) ? Wb : Wc;
        wbf[j] = f2bf(W[j & 262143]);
    }
}

// ---- transpose feat [t][b][c][p] f32 -> fa [t][(b,p)][c] bf16 ----
__global__ __launch_bounds__(256) void k_fa(const float* __restrict__ feat1,
                                            const float* __restrict__ feat2,
                                            const float* __restrict__ feat3,
                                            u16* __restrict__ fa) {
    const int tid = threadIdx.x;
    const int ct = blockIdx.x;
    const int t = blockIdx.y >> 7, b = blockIdx.y & 127;
    const float* feat = (t == 0) ? feat1 : (t == 1) ? feat2 : feat3;

    __shared__ u16 Ls[NP * 72];

    const int cl = tid >> 2;
    const int pc = tid & 3;
    const float* src = feat + ((size_t)b * NC + ct * 64 + cl) * NP + pc * 50;
#pragma unroll
    for (int u = 0; u < 50; u += 2) {
        float2 v = *(const float2*)(src + u);
        int p = pc * 50 + u;
        Ls[p * 72 + cl] = f2bf(v.x);
        Ls[(p + 1) * 72 + cl] = f2bf(v.y);
    }
    __syncthreads();
    for (int idx = tid; idx < 1600; idx += 256) {
        int p = idx >> 3, ck = idx & 7;
        uint4 v = *(const uint4*)&Ls[p * 72 + ck * 8];
        *(uint4*)&fa[((size_t)t * MROWS + b * NP + p) * NC + ct * 64 + ck * 8] = v;
    }
}

// ---- 1x1 conv as MFMA GEMM, XCD-aware 1D grid ----
// 2400 blocks; xcd = bid&7, local = bid>>3 in [0,300):
// mb = xcd*25 + local/12 (A-tile pinned to one XCD), (nb,t) = local%12.
// K-loop: m97-style single-buffer DMA schedule:
//   sync; STAGE(ks) global_load_lds; sync (drain); ds_read+MFMA
// 32KB staging -> 3 blocks/CU (VGPR-capped); cross-block wave overlap hides
// the per-step drain. DMA and ds_read phases are barrier-separated (no LDS
// port contention). No hand-counted waits -> count-robust, race-free.
// LDS tiles are linear [row][64] bf16 with 16B-chunk XOR swizzle:
// LDS[row][c] holds global chunk c ^ (row&7)  (both-sides involution).
__global__ __launch_bounds__(256) void k_conv1x1_mfma(
    const u16* __restrict__ fa, const u16* __restrict__ wbf,
    const float* __restrict__ ba, const float* __restrict__ bb,
    const float* __restrict__ bc, u16* __restrict__ fT) {
    const int tid = threadIdx.x;
    const int bid = blockIdx.x;
    const int xcd = bid & 7, local = bid >> 3;
    const int mb = xcd * 25 + local / 12;
    const int nbt = local % 12;
    const int nb = nbt & 3;
    const int t = nbt >> 2;
    const float* bias = (t == 0) ? ba : (t == 1) ? bb : bc;

    // staging: A [128][64] @0 (8192 u16), B [128][64] @8192. epilogue uses
    // [0, 17408) u16 = 34,816 B total block size -> 3 blocks/CU.
    __shared__ __align__(16) u16 smem[17408];

    const u16* Ag = fa + (size_t)t * MROWS * NC + (size_t)mb * 128 * NC;
    const u16* Bg = wbf + (size_t)t * NC * NC + (size_t)nb * 128 * NC;

    const int lane = tid & 63;
    const int wave = tid >> 6;
    const int wm = (wave & 1) * 64;
    const int wn = (wave >> 1) * 64;
    const int quad = lane >> 4;
    const int ln16 = lane & 15;

    const int r0 = lane >> 3;            // row within 8-row DMA chunk
    const int csrc = (lane & 7) ^ r0;    // pre-swizzled source 16B chunk

    f4 acc[4][4];
    const f4 zz = {0.f, 0.f, 0.f, 0.f};
#pragma unroll
    for (int i = 0; i < 4; ++i)
#pragma unroll
        for (int j = 0; j < 4; ++j) acc[i][j] = zz;

    // per wave per k-step: 4 A-chunks + 4 B-chunks = 8 DMA loads (1KB each)
#define STAGE1(ks) do {                                                        \
        int _ko = (ks) * 64 + csrc * 8;                                        \
        _Pragma("unroll")                                                      \
        for (int _i = 0; _i < 4; ++_i) {                                       \
            int _ra = wave * 32 + _i * 8;                                      \
            gload16(Ag + (size_t)(_ra + r0) * NC + _ko, &smem[_ra * 64]);      \
            gload16(Bg + (size_t)(_ra + r0) * NC + _ko,                        \
                    &smem[8192 + _ra * 64]);                                   \
        }                                                                      \
    } while (0)

#pragma unroll
    for (int ks = 0; ks < 8; ++ks) {
        __syncthreads();   // all readers of the buffer are done
        STAGE1(ks);
        __syncthreads();   // vmcnt(0) drain: tile resident in LDS
#pragma unroll
        for (int h = 0; h < 2; ++h) {
            bh8 afr[4], bfr[4];
#pragma unroll
            for (int s = 0; s < 4; ++s) {
                int cw = ((h * 4 + quad) ^ (ln16 & 7)) * 8;
                afr[s] = *(const bh8*)&smem[(wm + s * 16 + ln16) * 64 + cw];
                bfr[s] = *(const bh8*)&smem[8192 + (wn + s * 16 + ln16) * 64 + cw];
            }
#pragma unroll
            for (int i = 0; i < 4; ++i)
#pragma unroll
                for (int j = 0; j < 4; ++j)
                    acc[i][j] = __builtin_amdgcn_mfma_f32_16x16x32_bf16(
                        afr[i], bfr[j], acc[i][j], 0, 0, 0);
        }
    }
#undef STAGE1

    // epilogue: bias + bf16 pack into LDS tile [128][136], coalesced stores
    __syncthreads();
#pragma unroll
    for (int j = 0; j < 4; ++j) {
        int tcol = wn + j * 16 + ln16;
        float bi = bias[nb * 128 + tcol];
#pragma unroll
        for (int i = 0; i < 4; ++i) {
            int trow = wm + i * 16 + quad * 4;
#pragma unroll
            for (int r = 0; r < 4; ++r)
                smem[(trow + r) * 136 + tcol] = f2bf(acc[i][j][r] + bi);
        }
    }
    __syncthreads();
    const size_t obase = ((size_t)t * MROWS + (size_t)mb * 128) * NC + nb * 128;
#pragma unroll
    for (int it = 0; it < 8; ++it) {
        int idx = tid + 256 * it;
        int row = idx >> 4, ck = idx & 15;
        *(uint4*)(fT + obase + (size_t)row * NC + ck * 8) =
            *(const uint4*)&smem[row * 136 + ck * 8];
    }
}

// ---- Gram via MFMA; XCD-aware 1D grid ----
// 1536 blocks; m97-style single-buffer DMA schedule (see conv1x1).
// A tile 64x64 (2 DMA/wave) @0, B tile 256x64 (8 DMA/wave) @4096.
// Staging = 40,960 B; epilogue assembles output in TWO 32-row passes
// (28,672 B each) so the LDS block stays at 40,960 B -> 3 blocks/CU.
__global__ __launch_bounds__(256) void k_gram_mfma(const u16* __restrict__ fT,
                                                   u16* __restrict__ corr) {
    const int tid = threadIdx.x;
    const int bid = blockIdx.x;
    const int xcd = bid & 7, local = bid >> 3;
    const int gidx = xcd * 48 + (local >> 2);
    const int mt = local & 3;
    const int b = gidx / 3, pair = gidx % 3;
    const int tA = (pair == 2) ? 1 : 0;
    const int tB = (pair == 0) ? 1 : 2;

    __shared__ __align__(16) u16 smem[20480];   // 40,960 B

    const u16* Ag = fT + ((size_t)tA * NB + b) * NP * NC + (size_t)mt * 64 * NC;
    const u16* Bg = fT + ((size_t)tB * NB + b) * NP * NC;

    const int lane = tid & 63;
    const int wave = tid >> 6;
    const int wn = wave * 64;
    const int quad = lane >> 4;
    const int ln16 = lane & 15;

    const int r0 = lane >> 3;
    const int csrc = (lane & 7) ^ r0;

    f4 acc[4][4];
    const f4 zz = {0.f, 0.f, 0.f, 0.f};
#pragma unroll
    for (int i = 0; i < 4; ++i)
#pragma unroll
        for (int j = 0; j < 4; ++j) acc[i][j] = zz;

#define STAGE2(ks) do {                                                        \
        int _ko = (ks) * 64 + csrc * 8;                                        \
        _Pragma("unroll")                                                      \
        for (int _i = 0; _i < 2; ++_i) {                                       \
            int _ra = wave * 16 + _i * 8;                                      \
            gload16(Ag + (size_t)(_ra + r0) * NC + _ko, &smem[_ra * 64]);      \
        }                                                                      \
        _Pragma("unroll")                                                      \
        for (int _i = 0; _i < 8; ++_i) {                                       \
            int _rb = wave * 64 + _i * 8;                                      \
            gload16(Bg + (size_t)(_rb + r0) * NC + _ko,                        \
                    &smem[4096 + _rb * 64]);                                   \
        }                                                                      \
    } while (0)

#pragma unroll
    for (int ks = 0; ks < 8; ++ks) {
        __syncthreads();
        STAGE2(ks);
        __syncthreads();
#pragma unroll
        for (int h = 0; h < 2; ++h) {
            bh8 afr[4], bfr[4];
#pragma unroll
            for (int s = 0; s < 4; ++s) {
                int cw = ((h * 4 + quad) ^ (ln16 & 7)) * 8;
                afr[s] = *(const bh8*)&smem[(s * 16 + ln16) * 64 + cw];
                bfr[s] = *(const bh8*)&smem[4096 + (wn + s * 16 + ln16) * 64 + cw];
            }
#pragma unroll
            for (int i = 0; i < 4; ++i)
#pragma unroll
                for (int j = 0; j < 4; ++j)
                    acc[i][j] = __builtin_amdgcn_mfma_f32_16x16x32_bf16(
                        afr[i], bfr[j], acc[i][j], 0, 0, 0);
        }
    }
#undef STAGE2

    // epilogue, two 32-row passes: zero 32x448, scatter valid (p1,ch), write
    u16* Crow = corr + ((size_t)(b * 3 + pair)) * NP * NDP;
#pragma unroll
    for (int half = 0; half < 2; ++half) {
        __syncthreads();
        {
            const uint4 z4 = make_uint4(0, 0, 0, 0);
#pragma unroll
            for (int it = 0; it < 14; ++it)          // 32*448 u16 = 3584 uint4
                ((uint4*)smem)[tid + 256 * it] = z4;
        }
        __syncthreads();
#pragma unroll
        for (int i = half * 2; i < half * 2 + 2; ++i) {
#pragma unroll
            for (int r = 0; r < 4; ++r) {
                int p1l = i * 16 + quad * 4 + r;     // in [half*32, half*32+32)
                int lrow = p1l - half * 32;
                int p1 = mt * 64 + p1l;
                if (p1 >= NP) continue;
                int y1 = p1 / 20, x1 = p1 - y1 * 20;
#pragma unroll
                for (int j = 0; j < 4; ++j) {
                    int p2 = wn + j * 16 + ln16;
                    if (p2 >= NP) continue;
                    int y2 = p2 / 20, x2 = p2 - y2 * 20;
                    int oy = y2 - y1, ox = x2 - x1;
                    if (((oy | ox) & 1) == 0) {
                        int ch = ((oy + 20) >> 1) * 21 + ((ox + 20) >> 1);
                        float v = acc[i][j][r] * (1.0f / 512.0f);
                        v = (v > 0.0f) ? v : 0.1f * v;
                        smem[lrow * NDP + ch] = f2bf(v);
                    }
                }
            }
        }
        __syncthreads();
#pragma unroll
        for (int it = 0; it < 7; ++it) {             // 32 rows * 56 uint4
            int idx = tid + 256 * it;
            int row = idx / 56, cq = idx - row * 56;
            int p1 = mt * 64 + half * 32 + row;
            if (p1 < NP)
                *(uint4*)(Crow + (size_t)p1 * NDP + cq * 8) =
                    *(const uint4*)&smem[row * NDP + cq * 8];
        }
    }
}

#define LDA 72
// ---- both conv-GEMMs in one dispatch: grid (200, 2), y = mode ----
// mode 0: A = corr [b][pair][p][448], k = pair*448+ch, 21 k-iters
// mode 1: A = fT (3 stacked [25600][512]), k = t*512+c, 24 k-iters
__global__ __launch_bounds__(256) void k_convgemm(const u16* __restrict__ corr,
                                                  const u16* __restrict__ fT,
                                                  const u16* __restrict__ wctb,
                                                  const u16* __restrict__ wcatb,
                                                  float* __restrict__ Ucorr,
                                                  float* __restrict__ Ucat) {
    const int tid = threadIdx.x;
    const int mb = blockIdx.x;
    const int mode = blockIdx.y;
    const u16* A0 = mode ? fT : corr;
    const u16* Bn = mode ? wcatb : wctb;
    float* U = mode ? Ucat : Ucorr;
    const int kiters = mode ? (KCAT / 64) : (KCORR / 64);
    const int Kpad = kiters * 64;

    __shared__ __align__(16) u16 As[128 * LDA];
    __shared__ __align__(16) u16 Bs[32 * LDA];

    const int lane = tid & 63;
    const int wave = tid >> 6;
    const int wm = wave * 32;
    const int quad = lane >> 4;
    const int ln16 = lane & 15;

    size_t abase[4];
    int ack[4];
#pragma unroll
    for (int i = 0; i < 4; ++i) {
        int idx = tid + 256 * i;
        int r = idx >> 3;
        ack[i] = (idx & 7) * 8;
        int m = mb * 128 + r;
        if (mode == 0) {
            int b = m / NP, p = m - b * NP;
            abase[i] = ((size_t)(b * 3) * NP + p) * NDP;
        } else {
            abase[i] = (size_t)m * NC;
        }
    }

    f4 acc00 = {0,0,0,0}, acc01 = {0,0,0,0}, acc10 = {0,0,0,0}, acc11 = {0,0,0,0};

    uint4 ga[4], gb1;
#pragma unroll
    for (int i = 0; i < 4; ++i) {
        int k = ack[i];
        const u16* ap = (mode == 0)
            ? (A0 + abase[i] + (size_t)(k / NDP) * (NP * NDP) + (k % NDP))
            : (A0 + (size_t)(k >> 9) * MROWS * NC + abase[i] + (k & 511));
        ga[i] = *(const uint4*)ap;
    }
    {
        int r = tid >> 3, ck = tid & 7;
        gb1 = *(const uint4*)(Bn + (size_t)r * Kpad + ck * 8);
    }
    for (int ks = 0; ks < kiters; ++ks) {
        __syncthreads();
#pragma unroll
        for (int i = 0; i < 4; ++i) {
            int idx = tid + 256 * i;
            int r = idx >> 3, ck = idx & 7;
            *(uint4*)&As[r * LDA + ck * 8] = ga[i];
        }
        {
            int r = tid >> 3, ck = tid & 7;
            *(uint4*)&Bs[r * LDA + ck * 8] = gb1;
        }
        __syncthreads();
        if (ks < kiters - 1) {
            int kof = (ks + 1) * 64;
#pragma unroll
            for (int i = 0; i < 4; ++i) {
                int k = kof + ack[i];
                const u16* ap = (mode == 0)
                    ? (A0 + abase[i] + (size_t)(k / NDP) * (NP * NDP) + (k % NDP))
                    : (A0 + (size_t)(k >> 9) * MROWS * NC + abase[i] + (k & 511));
                ga[i] = *(const uint4*)ap;
            }
            int r = tid >> 3, ck = tid & 7;
            gb1 = *(const uint4*)(Bn + (size_t)r * Kpad + kof + ck * 8);
        }
#pragma unroll
        for (int h = 0; h < 2; ++h) {
            bh8 a0 = *(const bh8*)&As[(wm + ln16) * LDA + h * 32 + quad * 8];
            bh8 a1 = *(const bh8*)&As[(wm + 16 + ln16) * LDA + h * 32 + quad * 8];
            bh8 b0 = *(const bh8*)&Bs[(ln16) * LDA + h * 32 + quad * 8];
            bh8 b1 = *(const bh8*)&Bs[(16 + ln16) * LDA + h * 32 + quad * 8];
            acc00 = __builtin_amdgcn_mfma_f32_16x16x32_bf16(a0, b0, acc00, 0, 0, 0);
            acc01 = __builtin_amdgcn_mfma_f32_16x16x32_bf16(a0, b1, acc01, 0, 0, 0);
            acc10 = __builtin_amdgcn_mfma_f32_16x16x32_bf16(a1, b0, acc10, 0, 0, 0);
            acc11 = __builtin_amdgcn_mfma_f32_16x16x32_bf16(a1, b1, acc11, 0, 0, 0);
        }
    }
    const int rbase = mb * 128 + wm + quad * 4;
#pragma unroll
    for (int r = 0; r < 4; ++r) {
        U[(size_t)(rbase + r) * 32 + ln16] = acc00[r];
        U[(size_t)(rbase + r) * 32 + 16 + ln16] = acc01[r];
        U[(size_t)(rbase + 16 + r) * 32 + ln16] = acc10[r];
        U[(size_t)(rbase + 16 + r) * 32 + 16 + ln16] = acc11[r];
    }
}

// ---- merged tail: 9-neighbor gather + bias/relu + both MLPs + final linear ----
__global__ __launch_bounds__(256) void k_tail(
    const float* __restrict__ Ucorr, const float* __restrict__ Ucat,
    const float* __restrict__ bcorr, const float* __restrict__ bcat,
    const float* __restrict__ cf_w1, const float* __restrict__ cf_b1,
    const float* __restrict__ cf_w2, const float* __restrict__ cf_b2,
    const float* __restrict__ ccf_w1, const float* __restrict__ ccf_b1,
    const float* __restrict__ ccf_w2, const float* __restrict__ ccf_b2,
    const float* __restrict__ Wout, const float* __restrict__ bout,
    float* __restrict__ out) {
    const int tid = threadIdx.x;
    const int b = blockIdx.x;
    __shared__ float Lc[NP][28];
    __shared__ float La[NP][28];
    __shared__ float cv[600], vv[600], h1[256], h2a[128], h2b[128];
    for (int idx = tid; idx < NP * 27; idx += 256) {
        int p = idx / 27, n = idx - p * 27;
        Lc[p][n] = Ucorr[(size_t)(b * NP + p) * 32 + n];
        La[p][n] = Ucat[(size_t)(b * NP + p) * 32 + n];
    }
    __syncthreads();
    for (int idx = tid; idx < 1200; idx += 256) {
        int path = idx / 600;
        int rem = idx - path * 600;
        int o = rem / 200, p = rem - o * 200;
        int y = p / 20, x = p - y * 20;
        float s = (path == 0) ? bcorr[o] : bcat[o];
        for (int ky = 0; ky < 3; ++ky) {
            int yy = y + ky - 1;
            if (yy < 0 || yy >= NH) continue;
            for (int kx = 0; kx < 3; ++kx) {
                int xx = x + kx - 1;
                if (xx < 0 || xx >= NW) continue;
                int n = (ky * 3 + kx) * 3 + o;
                s += (path == 0) ? Lc[yy * 20 + xx][n] : La[yy * 20 + xx][n];
            }
        }
        if (path == 0) cv[rem] = fmaxf(s, 0.0f);
        else           vv[rem] = s;
    }
    __syncthreads();
    {
        float s = cf_b1[tid];
        const float* wr = cf_w1 + (size_t)tid * 600;
        for (int k = 0; k < 600; k += 4) {
            float4 wv = *(const float4*)&wr[k];
            s = fmaf(cv[k], wv.x, s); s = fmaf(cv[k + 1], wv.y, s);
            s = fmaf(cv[k + 2], wv.z, s); s = fmaf(cv[k + 3], wv.w, s);
        }
        h1[tid] = fmaxf(s, 0.0f);
    }
    __syncthreads();
    if (tid < 128) {
        float s = cf_b2[tid];
        const float* wr = cf_w2 + (size_t)tid * 256;
        for (int k = 0; k < 256; k += 4) {
            float4 wv = *(const float4*)&wr[k];
            s = fmaf(h1[k], wv.x, s); s = fmaf(h1[k + 1], wv.y, s);
            s = fmaf(h1[k + 2], wv.z, s); s = fmaf(h1[k + 3], wv.w, s);
        }
        h2a[tid] = fmaxf(s, 0.0f);
    }
    __syncthreads();
    {
        float s = ccf_b1[tid];
        const float* wr = ccf_w1 + (size_t)tid * 600;
        for (int k = 0; k < 600; k += 4) {
            float4 wv = *(const float4*)&wr[k];
            s = fmaf(vv[k], wv.x, s); s = fmaf(vv[k + 1], wv.y, s);
            s = fmaf(vv[k + 2], wv.z, s); s = fmaf(vv[k + 3], wv.w, s);
        }
        h1[tid] = fmaxf(s, 0.0f);
    }
    __syncthreads();
    if (tid < 128) {
        float s = ccf_b2[tid];
        const float* wr = ccf_w2 + (size_t)tid * 256;
        for (int k = 0; k < 256; k += 4) {
            float4 wv = *(const float4*)&wr[k];
            s = fmaf(h1[k], wv.x, s); s = fmaf(h1[k + 1], wv.y, s);
            s = fmaf(h1[k + 2], wv.z, s); s = fmaf(h1[k + 3], wv.w, s);
        }
        h2b[tid] = fmaxf(s, 0.0f);
    }
    __syncthreads();
    if (tid < 2) {
        float s = bout[tid];
        const float* wr = Wout + (size_t)tid * 256;
        for (int k = 0; k < 128; ++k) {
            s = fmaf(h2a[k], wr[k], s);
            s = fmaf(h2b[k], wr[128 + k], s);
        }
        out[(size_t)b * 2 + tid] = s;
    }
}

extern "C" void kernel_launch(void* const* d_in, const int* in_sizes, int n_in,
                              void* d_out, int out_size, void* d_ws, size_t ws_size,
                              hipStream_t stream) {
    const float* feat1  = (const float*)d_in[0];
    const float* feat2  = (const float*)d_in[1];
    const float* feat3  = (const float*)d_in[2];
    const float* Wa     = (const float*)d_in[3];
    const float* ba     = (const float*)d_in[4];
    const float* Wb     = (const float*)d_in[5];
    const float* bb     = (const float*)d_in[6];
    const float* Wc     = (const float*)d_in[7];
    const float* bc     = (const float*)d_in[8];
    const float* Wcorr  = (const float*)d_in[9];
    const float* bcorr  = (const float*)d_in[10];
    const float* Wcat   = (const float*)d_in[11];
    const float* bcat   = (const float*)d_in[12];
    const float* cf_w1  = (const float*)d_in[13];
    const float* cf_b1  = (const float*)d_in[14];
    const float* cf_w2  = (const float*)d_in[15];
    const float* cf_b2  = (const float*)d_in[16];
    const float* ccf_w1 = (const float*)d_in[17];
    const float* ccf_b1 = (const float*)d_in[18];
    const float* ccf_w2 = (const float*)d_in[19];
    const float* ccf_b2 = (const float*)d_in[20];
    const float* Wout   = (const float*)d_in[21];
    const float* bout   = (const float*)d_in[22];

    char* ws = (char*)d_ws;
    u16*  fa    = (u16*)(ws + OFF_FA);
    u16*  corr  = (u16*)(ws + OFF_CORR);     // aliases fa (disjoint lifetimes)
    float* Ucorr = (float*)(ws + OFF_UCORR);  // aliases fa tail
    float* Ucat  = (float*)(ws + OFF_UCAT);
    u16*  fT    = (u16*)(ws + OFF_FT);
    u16*  wbf   = (u16*)(ws + OFF_WBF);
    u16*  wctb  = (u16*)(ws + OFF_WCTB);
    u16*  wcatb = (u16*)(ws + OFF_WCATB);

    k_prep<<<3432, 256, 0, stream>>>(Wcorr, Wcat, Wa, Wb, Wc, wctb, wcatb, wbf);
    k_fa<<<dim3(8, 384), 256, 0, stream>>>(feat1, feat2, feat3, fa);
    k_conv1x1_mfma<<<2400, 256, 0, stream>>>(fa, wbf, ba, bb, bc, fT);
    // fa dead from here; gram writes every byte of corr (no memset needed)
    k_gram_mfma<<<1536, 256, 0, stream>>>(fT, corr);
    k_convgemm<<<dim3(200, 2), 256, 0, stream>>>(corr, fT, wctb, wcatb, Ucorr, Ucat);
    k_tail<<<128, 256, 0, stream>>>(Ucorr, Ucat, bcorr, bcat,
                                    cf_w1, cf_b1, cf_w2, cf_b2,
                                    ccf_w1, ccf_b1, ccf_w2, ccf_b2, Wout, bout,
                                    (float*)d_out);
}

// Round 4
// 451.001 us; speedup vs baseline: 1.5419x; 1.0008x over previous
//
#include <hip/hip_runtime.h>
#include <stdint.h>

#define NB 128
#define NC 512
#define NH 10
#define NW 20
#define NP 200      // NH*NW
#define ND3 1323
#define NDP 448     // per-pair padded channel row (441 -> 448, 896B aligned)
#define MROWS 25600 // NB*NP flattened GEMM rows per tensor
#define KCORR 1344  // 3*448 K extent for corr conv-GEMM
#define KCAT  1536  // 3*512

typedef unsigned short u16;
typedef unsigned int u32;

typedef short bh8 __attribute__((ext_vector_type(8)));   // 8 bf16 (4 VGPRs)
typedef float f4 __attribute__((ext_vector_type(4)));    // 4 fp32 acc

// ---- workspace layout (bytes) ----
// fa occupies [0, 78.6MB); dead after k_conv1x1_mfma. corr + Ucorr/Ucat alias it.
#define OFF_FA     0ULL
#define SZ_FA      (3ULL*MROWS*NC*2)             // 78,643,200
#define OFF_CORR   0ULL
#define SZ_CORR    (3ULL*NB*NP*NDP*2)            // 68,812,800  [b][pair][p][448]
#define OFF_UCORR  (OFF_CORR + SZ_CORR + 256)
#define SZ_U       (1ULL*MROWS*32*4)             // 3,276,800
#define OFF_UCAT   (OFF_UCORR + SZ_U)            // ends ~75.4MB < 78.6MB
#define OFF_FT     (OFF_FA + SZ_FA)
#define SZ_FT      (3ULL*MROWS*NC*2 + 65536)     // +64 pad rows for over-read
#define OFF_WBF    (OFF_FT + SZ_FT)
#define SZ_WBF     (3ULL*NC*NC*2)
#define OFF_WCTB   (OFF_WBF + SZ_WBF)
#define SZ_WCTB    (32ULL*KCORR*2)               // bf16 [32][1344]
#define OFF_WCATB  (OFF_WCTB + SZ_WCTB)
#define SZ_WCATB   (32ULL*KCAT*2)                // bf16 [32][1536]

__device__ __forceinline__ float bf2f(u16 a) {
    return __uint_as_float(((u32)a) << 16);
}
__device__ __forceinline__ u16 f2bf(float x) {
    u32 u = __float_as_uint(x);
    return (u16)((u + 0x7fffu + ((u >> 16) & 1u)) >> 16);
}

// direct global->LDS DMA, 16B per lane. lds dest must be wave-uniform base;
// HW scatters lane l to base + l*16.
__device__ __forceinline__ void gload16(const void* g, void* l) {
    __builtin_amdgcn_global_load_lds(
        (const __attribute__((address_space(1))) void*)g,
        (__attribute__((address_space(3))) void*)l, 16, 0, 0);
}

// ---- prep: build bf16 weight matrices ----
__global__ __launch_bounds__(256) void k_prep(const float* __restrict__ Wcorr,
                                              const float* __restrict__ Wcat,
                                              const float* __restrict__ Wa,
                                              const float* __restrict__ Wb,
                                              const float* __restrict__ Wc,
                                              u16* __restrict__ wctb,
                                              u16* __restrict__ wcatb,
                                              u16* __restrict__ wbf) {
    int idx = blockIdx.x * 256 + threadIdx.x;
    const int n1 = 32 * KCORR;     // 43008
    const int n2 = 32 * KCAT;      // 49152
    const int n3 = 3 * NC * NC;    // 786432
    if (idx < n1) {
        int k = idx % KCORR;
        int n = idx / KCORR;
        int pair = k / NDP, ch = k - pair * NDP;
        float v = 0.0f;
        if (n < 27 && ch < 441) {
            int d = pair * 441 + ch;
            int tap = n / 3, o = n % 3;
            int ky = tap / 3, kx = tap % 3;
            v = Wcorr[((o * ND3 + d) * 3 + ky) * 3 + kx];
        }
        wctb[idx] = f2bf(v);
    } else if (idx < n1 + n2) {
        int j = idx - n1;
        int i = j % KCAT;
        int n = j / KCAT;
        float v = 0.0f;
        if (n < 27) {
            int tap = n / 3, o = n % 3;
            int ky = tap / 3, kx = tap % 3;
            v = Wcat[((o * 1536 + i) * 3 + ky) * 3 + kx];
        }
        wcatb[j] = f2bf(v);
    } else if (idx < n1 + n2 + n3) {
        int j = idx - n1 - n2;
        int t = j >> 18;
        const float* W = (t == 0) ? Wa : (t == 1) ? Wb : Wc;
        wbf[j] = f2bf(W[j & 262143]);
    }
}

// ---- transpose feat [t][b][c][p] f32 -> fa [t][(b,p)][c] bf16 ----
__global__ __launch_bounds__(256) void k_fa(const float* __restrict__ feat1,
                                            const float* __restrict__ feat2,
                                            const float* __restrict__ feat3,
                                            u16* __restrict__ fa) {
    const int tid = threadIdx.x;
    const int ct = blockIdx.x;
    const int t = blockIdx.y >> 7, b = blockIdx.y & 127;
    const float* feat = (t == 0) ? feat1 : (t == 1) ? feat2 : feat3;

    __shared__ u16 Ls[NP * 72];

    const int cl = tid >> 2;
    const int pc = tid & 3;
    const float* src = feat + ((size_t)b * NC + ct * 64 + cl) * NP + pc * 50;
#pragma unroll
    for (int u = 0; u < 50; u += 2) {
        float2 v = *(const float2*)(src + u);
        int p = pc * 50 + u;
        Ls[p * 72 + cl] = f2bf(v.x);
        Ls[(p + 1) * 72 + cl] = f2bf(v.y);
    }
    __syncthreads();
    for (int idx = tid; idx < 1600; idx += 256) {
        int p = idx >> 3, ck = idx & 7;
        uint4 v = *(const uint4*)&Ls[p * 72 + ck * 8];
        *(uint4*)&fa[((size_t)t * MROWS + b * NP + p) * NC + ct * 64 + ck * 8] = v;
    }
}

// ---- 1x1 conv as MFMA GEMM, XCD-aware 1D grid ----
// 2400 blocks; xcd = bid&7, local = bid>>3 in [0,300):
// mb = xcd*25 + local/12 (A-tile pinned to one XCD), (nb,t) = local%12.
// K-loop: m97-style single-buffer DMA schedule:
//   sync; STAGE(ks) global_load_lds; sync (drain); ds_read+MFMA
// 32KB staging -> 3 blocks/CU (VGPR-capped); cross-block wave overlap hides
// the per-step drain. DMA and ds_read phases are barrier-separated (no LDS
// port contention). No hand-counted waits -> count-robust, race-free.
// LDS tiles are linear [row][64] bf16 with 16B-chunk XOR swizzle:
// LDS[row][c] holds global chunk c ^ (row&7)  (both-sides involution).
__global__ __launch_bounds__(256) void k_conv1x1_mfma(
    const u16* __restrict__ fa, const u16* __restrict__ wbf,
    const float* __restrict__ ba, const float* __restrict__ bb,
    const float* __restrict__ bc, u16* __restrict__ fT) {
    const int tid = threadIdx.x;
    const int bid = blockIdx.x;
    const int xcd = bid & 7, local = bid >> 3;
    const int mb = xcd * 25 + local / 12;
    const int nbt = local % 12;
    const int nb = nbt & 3;
    const int t = nbt >> 2;
    const float* bias = (t == 0) ? ba : (t == 1) ? bb : bc;

    // staging: A [128][64] @0 (8192 u16), B [128][64] @8192. epilogue uses
    // [0, 17408) u16 = 34,816 B total block size -> 3 blocks/CU.
    __shared__ __align__(16) u16 smem[17408];

    const u16* Ag = fa + (size_t)t * MROWS * NC + (size_t)mb * 128 * NC;
    const u16* Bg = wbf + (size_t)t * NC * NC + (size_t)nb * 128 * NC;

    const int lane = tid & 63;
    const int wave = tid >> 6;
    const int wm = (wave & 1) * 64;
    const int wn = (wave >> 1) * 64;
    const int quad = lane >> 4;
    const int ln16 = lane & 15;

    const int r0 = lane >> 3;            // row within 8-row DMA chunk
    const int csrc = (lane & 7) ^ r0;    // pre-swizzled source 16B chunk

    f4 acc[4][4];
    const f4 zz = {0.f, 0.f, 0.f, 0.f};
#pragma unroll
    for (int i = 0; i < 4; ++i)
#pragma unroll
        for (int j = 0; j < 4; ++j) acc[i][j] = zz;

    // per wave per k-step: 4 A-chunks + 4 B-chunks = 8 DMA loads (1KB each)
#define STAGE1(ks) do {                                                        \
        int _ko = (ks) * 64 + csrc * 8;                                        \
        _Pragma("unroll")                                                      \
        for (int _i = 0; _i < 4; ++_i) {                                       \
            int _ra = wave * 32 + _i * 8;                                      \
            gload16(Ag + (size_t)(_ra + r0) * NC + _ko, &smem[_ra * 64]);      \
            gload16(Bg + (size_t)(_ra + r0) * NC + _ko,                        \
                    &smem[8192 + _ra * 64]);                                   \
        }                                                                      \
    } while (0)

#pragma unroll
    for (int ks = 0; ks < 8; ++ks) {
        __syncthreads();   // all readers of the buffer are done
        STAGE1(ks);
        __syncthreads();   // vmcnt(0) drain: tile resident in LDS
#pragma unroll
        for (int h = 0; h < 2; ++h) {
            bh8 afr[4], bfr[4];
#pragma unroll
            for (int s = 0; s < 4; ++s) {
                int cw = ((h * 4 + quad) ^ (ln16 & 7)) * 8;
                afr[s] = *(const bh8*)&smem[(wm + s * 16 + ln16) * 64 + cw];
                bfr[s] = *(const bh8*)&smem[8192 + (wn + s * 16 + ln16) * 64 + cw];
            }
#pragma unroll
            for (int i = 0; i < 4; ++i)
#pragma unroll
                for (int j = 0; j < 4; ++j)
                    acc[i][j] = __builtin_amdgcn_mfma_f32_16x16x32_bf16(
                        afr[i], bfr[j], acc[i][j], 0, 0, 0);
        }
    }
#undef STAGE1

    // epilogue: bias + bf16 pack into LDS tile [128][136], coalesced stores
    __syncthreads();
#pragma unroll
    for (int j = 0; j < 4; ++j) {
        int tcol = wn + j * 16 + ln16;
        float bi = bias[nb * 128 + tcol];
#pragma unroll
        for (int i = 0; i < 4; ++i) {
            int trow = wm + i * 16 + quad * 4;
#pragma unroll
            for (int r = 0; r < 4; ++r)
                smem[(trow + r) * 136 + tcol] = f2bf(acc[i][j][r] + bi);
        }
    }
    __syncthreads();
    const size_t obase = ((size_t)t * MROWS + (size_t)mb * 128) * NC + nb * 128;
#pragma unroll
    for (int it = 0; it < 8; ++it) {
        int idx = tid + 256 * it;
        int row = idx >> 4, ck = idx & 15;
        *(uint4*)(fT + obase + (size_t)row * NC + ck * 8) =
            *(const uint4*)&smem[row * 136 + ck * 8];
    }
}

// ---- Gram via MFMA; XCD-aware 1D grid ----
// 1536 blocks; m97-style single-buffer DMA schedule (see conv1x1).
// A tile 64x64 (2 DMA/wave) @0, B tile 256x64 (8 DMA/wave) @4096.
// Staging = 40,960 B; epilogue assembles output in TWO 32-row passes
// (28,672 B each) so the LDS block stays at 40,960 B -> 3 blocks/CU.
__global__ __launch_bounds__(256) void k_gram_mfma(const u16* __restrict__ fT,
                                                   u16* __restrict__ corr) {
    const int tid = threadIdx.x;
    const int bid = blockIdx.x;
    const int xcd = bid & 7, local = bid >> 3;
    const int gidx = xcd * 48 + (local >> 2);
    const int mt = local & 3;
    const int b = gidx / 3, pair = gidx % 3;
    const int tA = (pair == 2) ? 1 : 0;
    const int tB = (pair == 0) ? 1 : 2;

    __shared__ __align__(16) u16 smem[20480];   // 40,960 B

    const u16* Ag = fT + ((size_t)tA * NB + b) * NP * NC + (size_t)mt * 64 * NC;
    const u16* Bg = fT + ((size_t)tB * NB + b) * NP * NC;

    const int lane = tid & 63;
    const int wave = tid >> 6;
    const int wn = wave * 64;
    const int quad = lane >> 4;
    const int ln16 = lane & 15;

    const int r0 = lane >> 3;
    const int csrc = (lane & 7) ^ r0;

    f4 acc[4][4];
    const f4 zz = {0.f, 0.f, 0.f, 0.f};
#pragma unroll
    for (int i = 0; i < 4; ++i)
#pragma unroll
        for (int j = 0; j < 4; ++j) acc[i][j] = zz;

#define STAGE2(ks) do {                                                        \
        int _ko = (ks) * 64 + csrc * 8;                                        \
        _Pragma("unroll")                                                      \
        for (int _i = 0; _i < 2; ++_i) {                                       \
            int _ra = wave * 16 + _i * 8;                                      \
            gload16(Ag + (size_t)(_ra + r0) * NC + _ko, &smem[_ra * 64]);      \
        }                                                                      \
        _Pragma("unroll")                                                      \
        for (int _i = 0; _i < 8; ++_i) {                                       \
            int _rb = wave * 64 + _i * 8;                                      \
            gload16(Bg + (size_t)(_rb + r0) * NC + _ko,                        \
                    &smem[4096 + _rb * 64]);                                   \
        }                                                                      \
    } while (0)

#pragma unroll
    for (int ks = 0; ks < 8; ++ks) {
        __syncthreads();
        STAGE2(ks);
        __syncthreads();
#pragma unroll
        for (int h = 0; h < 2; ++h) {
            bh8 afr[4], bfr[4];
#pragma unroll
            for (int s = 0; s < 4; ++s) {
                int cw = ((h * 4 + quad) ^ (ln16 & 7)) * 8;
                afr[s] = *(const bh8*)&smem[(s * 16 + ln16) * 64 + cw];
                bfr[s] = *(const bh8*)&smem[4096 + (wn + s * 16 + ln16) * 64 + cw];
            }
#pragma unroll
            for (int i = 0; i < 4; ++i)
#pragma unroll
                for (int j = 0; j < 4; ++j)
                    acc[i][j] = __builtin_amdgcn_mfma_f32_16x16x32_bf16(
                        afr[i], bfr[j], acc[i][j], 0, 0, 0);
        }
    }
#undef STAGE2

    // epilogue, two 32-row passes: zero 32x448, scatter valid (p1,ch), write
    u16* Crow = corr + ((size_t)(b * 3 + pair)) * NP * NDP;
#pragma unroll
    for (int half = 0; half < 2; ++half) {
        __syncthreads();
        {
            const uint4 z4 = make_uint4(0, 0, 0, 0);
#pragma unroll
            for (int it = 0; it < 14; ++it)          // 32*448 u16 = 3584 uint4
                ((uint4*)smem)[tid + 256 * it] = z4;
        }
        __syncthreads();
#pragma unroll
        for (int i = half * 2; i < half * 2 + 2; ++i) {
#pragma unroll
            for (int r = 0; r < 4; ++r) {
                int p1l = i * 16 + quad * 4 + r;     // in [half*32, half*32+32)
                int lrow = p1l - half * 32;
                int p1 = mt * 64 + p1l;
                if (p1 >= NP) continue;
                int y1 = p1 / 20, x1 = p1 - y1 * 20;
#pragma unroll
                for (int j = 0; j < 4; ++j) {
                    int p2 = wn + j * 16 + ln16;
                    if (p2 >= NP) continue;
                    int y2 = p2 / 20, x2 = p2 - y2 * 20;
                    int oy = y2 - y1, ox = x2 - x1;
                    if (((oy | ox) & 1) == 0) {
                        int ch = ((oy + 20) >> 1) * 21 + ((ox + 20) >> 1);
                        float v = acc[i][j][r] * (1.0f / 512.0f);
                        v = (v > 0.0f) ? v : 0.1f * v;
                        smem[lrow * NDP + ch] = f2bf(v);
                    }
                }
            }
        }
        __syncthreads();
#pragma unroll
        for (int it = 0; it < 7; ++it) {             // 32 rows * 56 uint4
            int idx = tid + 256 * it;
            int row = idx / 56, cq = idx - row * 56;
            int p1 = mt * 64 + half * 32 + row;
            if (p1 < NP)
                *(uint4*)(Crow + (size_t)p1 * NDP + cq * 8) =
                    *(const uint4*)&smem[row * NDP + cq * 8];
        }
    }
}

// ---- both conv-GEMMs in one dispatch: grid (400, 2), y = mode ----
// N=32 GEMM = memory stream; A rows are wave-private (zero reuse) and B
// (86-98KB) is L1/L2-resident -> LDS staging + barriers were pure overhead.
// Barrier-free, LDS-free register-fragment version: each wave owns 16 rows,
// loads A/B fragments directly from global, 2-deep register prefetch
// (literal buffer indices; rule #20). Accumulation order (ks, then h) is
// identical to the LDS version -> bitwise-same results.
// mode 0: A = corr [b][pair][p][448], k = pair*448+ch, 21 k-iters
// mode 1: A = fT (3 stacked [25600][512]), k = t*512+c, 24 k-iters
__global__ __launch_bounds__(256) void k_convgemm(const u16* __restrict__ corr,
                                                  const u16* __restrict__ fT,
                                                  const u16* __restrict__ wctb,
                                                  const u16* __restrict__ wcatb,
                                                  float* __restrict__ Ucorr,
                                                  float* __restrict__ Ucat) {
    const int tid = threadIdx.x;
    const int mode = blockIdx.y;
    const u16* A0 = mode ? fT : corr;
    const u16* Bn = mode ? wcatb : wctb;
    float* U = mode ? Ucat : Ucorr;
    const int kiters = mode ? (KCAT / 64) : (KCORR / 64);
    const int Kpad = kiters * 64;

    const int lane = tid & 63;
    const int wave = tid >> 6;
    const int quad = lane >> 4;
    const int ln16 = lane & 15;
    const int wbase = (blockIdx.x * 4 + wave) * 16;   // wave's 16 output rows
    const int arow = wbase + ln16;                    // this lane's A row

    size_t abase;
    if (mode == 0) {
        int b = arow / NP, p = arow - b * NP;
        abase = ((size_t)(b * 3) * NP + p) * NDP;
    } else {
        abase = (size_t)arow * NC;
    }

    f4 acc0 = {0, 0, 0, 0}, acc1 = {0, 0, 0, 0};

    bh8 pa[2][2], pb0[2][2], pb1[2][2];   // [buf][h], literal-indexed only

#define PFC(buf, ks) do {                                                      \
        _Pragma("unroll")                                                      \
        for (int _h = 0; _h < 2; ++_h) {                                       \
            int _k = (ks) * 64 + _h * 32 + quad * 8;                           \
            const u16* _ap;                                                    \
            if (mode == 0) {                                                   \
                int _pr = _k / NDP;                                            \
                _ap = A0 + abase + (size_t)_pr * (NP * NDP) + (_k - _pr * NDP);\
            } else {                                                           \
                _ap = A0 + (size_t)(_k >> 9) * ((size_t)MROWS * NC) + abase    \
                      + (_k & 511);                                            \
            }                                                                  \
            pa[buf][_h]  = *(const bh8*)_ap;                                   \
            pb0[buf][_h] = *(const bh8*)(Bn + (size_t)ln16 * Kpad + _k);       \
            pb1[buf][_h] = *(const bh8*)(Bn + (size_t)(16 + ln16) * Kpad + _k);\
        }                                                                      \
    } while (0)

#define CGM(buf) do {                                                          \
        acc0 = __builtin_amdgcn_mfma_f32_16x16x32_bf16(pa[buf][0],             \
                   pb0[buf][0], acc0, 0, 0, 0);                                \
        acc1 = __builtin_amdgcn_mfma_f32_16x16x32_bf16(pa[buf][0],             \
                   pb1[buf][0], acc1, 0, 0, 0);                                \
        acc0 = __builtin_amdgcn_mfma_f32_16x16x32_bf16(pa[buf][1],             \
                   pb0[buf][1], acc0, 0, 0, 0);                                \
        acc1 = __builtin_amdgcn_mfma_f32_16x16x32_bf16(pa[buf][1],             \
                   pb1[buf][1], acc1, 0, 0, 0);                                \
    } while (0)

    PFC(0, 0);
    PFC(1, 1);
    int ks = 0;
    for (; ks + 1 < kiters; ks += 2) {
        CGM(0);
        if (ks + 2 < kiters) PFC(0, ks + 2);
        CGM(1);
        if (ks + 3 < kiters) PFC(1, ks + 3);
    }
    if (ks < kiters) CGM(0);   // odd kiters tail (mode 0: 21 steps)
#undef PFC
#undef CGM

    const int orow = wbase + quad * 4;
#pragma unroll
    for (int r = 0; r < 4; ++r) {
        U[(size_t)(orow + r) * 32 + ln16] = acc0[r];
        U[(size_t)(orow + r) * 32 + 16 + ln16] = acc1[r];
    }
}

// ---- merged tail: 9-neighbor gather + bias/relu + both MLPs + final linear ----
__global__ __launch_bounds__(256) void k_tail(
    const float* __restrict__ Ucorr, const float* __restrict__ Ucat,
    const float* __restrict__ bcorr, const float* __restrict__ bcat,
    const float* __restrict__ cf_w1, const float* __restrict__ cf_b1,
    const float* __restrict__ cf_w2, const float* __restrict__ cf_b2,
    const float* __restrict__ ccf_w1, const float* __restrict__ ccf_b1,
    const float* __restrict__ ccf_w2, const float* __restrict__ ccf_b2,
    const float* __restrict__ Wout, const float* __restrict__ bout,
    float* __restrict__ out) {
    const int tid = threadIdx.x;
    const int b = blockIdx.x;
    __shared__ float Lc[NP][28];
    __shared__ float La[NP][28];
    __shared__ float cv[600], vv[600], h1[256], h2a[128], h2b[128];
    for (int idx = tid; idx < NP * 27; idx += 256) {
        int p = idx / 27, n = idx - p * 27;
        Lc[p][n] = Ucorr[(size_t)(b * NP + p) * 32 + n];
        La[p][n] = Ucat[(size_t)(b * NP + p) * 32 + n];
    }
    __syncthreads();
    for (int idx = tid; idx < 1200; idx += 256) {
        int path = idx / 600;
        int rem = idx - path * 600;
        int o = rem / 200, p = rem - o * 200;
        int y = p / 20, x = p - y * 20;
        float s = (path == 0) ? bcorr[o] : bcat[o];
        for (int ky = 0; ky < 3; ++ky) {
            int yy = y + ky - 1;
            if (yy < 0 || yy >= NH) continue;
            for (int kx = 0; kx < 3; ++kx) {
                int xx = x + kx - 1;
                if (xx < 0 || xx >= NW) continue;
                int n = (ky * 3 + kx) * 3 + o;
                s += (path == 0) ? Lc[yy * 20 + xx][n] : La[yy * 20 + xx][n];
            }
        }
        if (path == 0) cv[rem] = fmaxf(s, 0.0f);
        else           vv[rem] = s;
    }
    __syncthreads();
    {
        float s = cf_b1[tid];
        const float* wr = cf_w1 + (size_t)tid * 600;
        for (int k = 0; k < 600; k += 4) {
            float4 wv = *(const float4*)&wr[k];
            s = fmaf(cv[k], wv.x, s); s = fmaf(cv[k + 1], wv.y, s);
            s = fmaf(cv[k + 2], wv.z, s); s = fmaf(cv[k + 3], wv.w, s);
        }
        h1[tid] = fmaxf(s, 0.0f);
    }
    __syncthreads();
    if (tid < 128) {
        float s = cf_b2[tid];
        const float* wr = cf_w2 + (size_t)tid * 256;
        for (int k = 0; k < 256; k += 4) {
            float4 wv = *(const float4*)&wr[k];
            s = fmaf(h1[k], wv.x, s); s = fmaf(h1[k + 1], wv.y, s);
            s = fmaf(h1[k + 2], wv.z, s); s = fmaf(h1[k + 3], wv.w, s);
        }
        h2a[tid] = fmaxf(s, 0.0f);
    }
    __syncthreads();
    {
        float s = ccf_b1[tid];
        const float* wr = ccf_w1 + (size_t)tid * 600;
        for (int k = 0; k < 600; k += 4) {
            float4 wv = *(const float4*)&wr[k];
            s = fmaf(vv[k], wv.x, s); s = fmaf(vv[k + 1], wv.y, s);
            s = fmaf(vv[k + 2], wv.z, s); s = fmaf(vv[k + 3], wv.w, s);
        }
        h1[tid] = fmaxf(s, 0.0f);
    }
    __syncthreads();
    if (tid < 128) {
        float s = ccf_b2[tid];
        const float* wr = ccf_w2 + (size_t)tid * 256;
        for (int k = 0; k < 256; k += 4) {
            float4 wv = *(const float4*)&wr[k];
            s = fmaf(h1[k], wv.x, s); s = fmaf(h1[k + 1], wv.y, s);
            s = fmaf(h1[k + 2], wv.z, s); s = fmaf(h1[k + 3], wv.w, s);
        }
        h2b[tid] = fmaxf(s, 0.0f);
    }
    __syncthreads();
    if (tid < 2) {
        float s = bout[tid];
        const float* wr = Wout + (size_t)tid * 256;
        for (int k = 0; k < 128; ++k) {
            s = fmaf(h2a[k], wr[k], s);
            s = fmaf(h2b[k], wr[128 + k], s);
        }
        out[(size_t)b * 2 + tid] = s;
    }
}

extern "C" void kernel_launch(void* const* d_in, const int* in_sizes, int n_in,
                              void* d_out, int out_size, void* d_ws, size_t ws_size,
                              hipStream_t stream) {
    const float* feat1  = (const float*)d_in[0];
    const float* feat2  = (const float*)d_in[1];
    const float* feat3  = (const float*)d_in[2];
    const float* Wa     = (const float*)d_in[3];
    const float* ba     = (const float*)d_in[4];
    const float* Wb     = (const float*)d_in[5];
    const float* bb     = (const float*)d_in[6];
    const float* Wc     = (const float*)d_in[7];
    const float* bc     = (const float*)d_in[8];
    const float* Wcorr  = (const float*)d_in[9];
    const float* bcorr  = (const float*)d_in[10];
    const float* Wcat   = (const float*)d_in[11];
    const float* bcat   = (const float*)d_in[12];
    const float* cf_w1  = (const float*)d_in[13];
    const float* cf_b1  = (const float*)d_in[14];
    const float* cf_w2  = (const float*)d_in[15];
    const float* cf_b2  = (const float*)d_in[16];
    const float* ccf_w1 = (const float*)d_in[17];
    const float* ccf_b1 = (const float*)d_in[18];
    const float* ccf_w2 = (const float*)d_in[19];
    const float* ccf_b2 = (const float*)d_in[20];
    const float* Wout   = (const float*)d_in[21];
    const float* bout   = (const float*)d_in[22];

    char* ws = (char*)d_ws;
    u16*  fa    = (u16*)(ws + OFF_FA);
    u16*  corr  = (u16*)(ws + OFF_CORR);     // aliases fa (disjoint lifetimes)
    float* Ucorr = (float*)(ws + OFF_UCORR);  // aliases fa tail
    float* Ucat  = (float*)(ws + OFF_UCAT);
    u16*  fT    = (u16*)(ws + OFF_FT);
    u16*  wbf   = (u16*)(ws + OFF_WBF);
    u16*  wctb  = (u16*)(ws + OFF_WCTB);
    u16*  wcatb = (u16*)(ws + OFF_WCATB);

    k_prep<<<3432, 256, 0, stream>>>(Wcorr, Wcat, Wa, Wb, Wc, wctb, wcatb, wbf);
    k_fa<<<dim3(8, 384), 256, 0, stream>>>(feat1, feat2, feat3, fa);
    k_conv1x1_mfma<<<2400, 256, 0, stream>>>(fa, wbf, ba, bb, bc, fT);
    // fa dead from here; gram writes every byte of corr (no memset needed)
    k_gram_mfma<<<1536, 256, 0, stream>>>(fT, corr);
    k_convgemm<<<dim3(400, 2), 256, 0, stream>>>(corr, fT, wctb, wcatb, Ucorr, Ucat);
    k_tail<<<128, 256, 0, stream>>>(Ucorr, Ucat, bcorr, bcat,
                                    cf_w1, cf_b1, cf_w2, cf_b2,
                                    ccf_w1, ccf_b1, ccf_w2, ccf_b2, Wout, bout,
                                    (float*)d_out);
}

// Round 5
// 447.411 us; speedup vs baseline: 1.5542x; 1.0080x over previous
//
#include <hip/hip_runtime.h>
#include <stdint.h>

#define NB 128
#define NC 512
#define NH 10
#define NW 20
#define NP 200      // NH*NW
#define ND3 1323
#define NDP 448     // per-pair padded channel row (441 -> 448, 896B aligned)
#define MROWS 25600 // NB*NP flattened GEMM rows per tensor
#define KCORR 1344  // 3*448 K extent for corr conv-GEMM
#define KCAT  1536  // 3*512

typedef unsigned short u16;
typedef unsigned int u32;

typedef short bh8 __attribute__((ext_vector_type(8)));   // 8 bf16 (4 VGPRs)
typedef float f4 __attribute__((ext_vector_type(4)));    // 4 fp32 acc

// ---- workspace layout (bytes) ----
#define OFF_FA     0ULL
#define SZ_FA      (3ULL*MROWS*NC*2)             // 78,643,200
#define OFF_CORR   0ULL
#define SZ_CORR    (3ULL*NB*NP*NDP*2)            // 68,812,800  [b][pair][p][448]
#define OFF_UCORR  (OFF_CORR + SZ_CORR + 256)
#define SZ_U       (1ULL*MROWS*32*4)             // 3,276,800
#define OFF_UCAT   (OFF_UCORR + SZ_U)            // ends ~75.4MB < 78.6MB
#define OFF_FT     (OFF_FA + SZ_FA)
#define SZ_FT      (3ULL*MROWS*NC*2 + 65536)     // +64 pad rows for over-read
#define OFF_WBF    (OFF_FT + SZ_FT)
#define SZ_WBF     (3ULL*NC*NC*2)
#define OFF_WCTB   (OFF_WBF + SZ_WBF)
#define SZ_WCTB    (32ULL*KCORR*2)               // bf16 [32][1344]
#define OFF_WCATB  (OFF_WCTB + SZ_WCTB)
#define SZ_WCATB   (32ULL*KCAT*2)                // bf16 [32][1536]

__device__ __forceinline__ float bf2f(u16 a) {
    return __uint_as_float(((u32)a) << 16);
}
__device__ __forceinline__ u16 f2bf(float x) {
    u32 u = __float_as_uint(x);
    return (u16)((u + 0x7fffu + ((u >> 16) & 1u)) >> 16);
}

// direct global->LDS DMA, 16B per lane. lds dest must be wave-uniform base;
// HW scatters lane l to base + l*16.
__device__ __forceinline__ void gload16(const void* g, void* l) {
    __builtin_amdgcn_global_load_lds(
        (const __attribute__((address_space(1))) void*)g,
        (__attribute__((address_space(3))) void*)l, 16, 0, 0);
}

// ---- merged prep + transpose: one launch ----
// blocks [0,3072): fa transpose (ct = bid&7, y = bid>>3)
// blocks [3072,6504): bf16 weight prep
__global__ __launch_bounds__(256) void k_prep_fa(
    const float* __restrict__ feat1, const float* __restrict__ feat2,
    const float* __restrict__ feat3, u16* __restrict__ fa,
    const float* __restrict__ Wcorr, const float* __restrict__ Wcat,
    const float* __restrict__ Wa, const float* __restrict__ Wb,
    const float* __restrict__ Wc, u16* __restrict__ wctb,
    u16* __restrict__ wcatb, u16* __restrict__ wbf) {
    const int tid = threadIdx.x;
    const int bid = blockIdx.x;
    if (bid < 3072) {
        const int ct = bid & 7;
        const int yy = bid >> 3;
        const int t = yy >> 7, b = yy & 127;
        const float* feat = (t == 0) ? feat1 : (t == 1) ? feat2 : feat3;

        __shared__ u16 Ls[NP * 72];

        const int cl = tid >> 2;
        const int pc = tid & 3;
        const float* src = feat + ((size_t)b * NC + ct * 64 + cl) * NP + pc * 50;
#pragma unroll
        for (int u = 0; u < 50; u += 2) {
            float2 v = *(const float2*)(src + u);
            int p = pc * 50 + u;
            Ls[p * 72 + cl] = f2bf(v.x);
            Ls[(p + 1) * 72 + cl] = f2bf(v.y);
        }
        __syncthreads();
        for (int idx = tid; idx < 1600; idx += 256) {
            int p = idx >> 3, ck = idx & 7;
            uint4 v = *(const uint4*)&Ls[p * 72 + ck * 8];
            *(uint4*)&fa[((size_t)t * MROWS + b * NP + p) * NC + ct * 64 + ck * 8] = v;
        }
    } else {
        int idx = (bid - 3072) * 256 + tid;
        const int n1 = 32 * KCORR;     // 43008
        const int n2 = 32 * KCAT;      // 49152
        const int n3 = 3 * NC * NC;    // 786432
        if (idx < n1) {
            int k = idx % KCORR;
            int n = idx / KCORR;
            int pair = k / NDP, ch = k - pair * NDP;
            float v = 0.0f;
            if (n < 27 && ch < 441) {
                int d = pair * 441 + ch;
                int tap = n / 3, o = n % 3;
                int ky = tap / 3, kx = tap % 3;
                v = Wcorr[((o * ND3 + d) * 3 + ky) * 3 + kx];
            }
            wctb[idx] = f2bf(v);
        } else if (idx < n1 + n2) {
            int j = idx - n1;
            int i = j % KCAT;
            int n = j / KCAT;
            float v = 0.0f;
            if (n < 27) {
                int tap = n / 3, o = n % 3;
                int ky = tap / 3, kx = tap % 3;
                v = Wcat[((o * 1536 + i) * 3 + ky) * 3 + kx];
            }
            wcatb[j] = f2bf(v);
        } else if (idx < n1 + n2 + n3) {
            int j = idx - n1 - n2;
            int t = j >> 18;
            const float* W = (t == 0) ? Wa : (t == 1) ? Wb : Wc;
            wbf[j] = f2bf(W[j & 262143]);
        }
    }
}

// ---- 1x1 conv as MFMA GEMM, XCD-aware 1D grid ----
// 2400 blocks; xcd = bid&7, local = bid>>3; mb = xcd*25 + local/12.
// Counted-vmcnt double-buffered DMA pipeline at BK=32:
//   prologue: preload bias (4 VMEM) + vmcnt(0) drain -> loop VMEM = DMAs only.
//   16 k-steps: vmcnt(4) [drain current buf, keep next in flight]; barrier;
//   ds_read+16 MFMA; barrier; STAGE(buf, ks+2).  Never drains to 0 in-loop.
// dbuf = 32KB, unions with 34.8KB epilogue -> LDS 34,816B, 3 blocks/CU.
// LDS chunk swizzle: slot q_s at row r holds global chunk q_s ^ (r&3) ^
// ((r>>2)&3)  -> ds_read_b128 fragments are 2-way (free).  Source side
// pre-swizzled: csrc = (l&3)^((l>>2)&3)^((l>>4)&3) (chunk-independent).
// k ascends in 32-slices, identical per-acc MFMA order as before -> bitwise
// same results.
__global__ __launch_bounds__(256) void k_conv1x1_mfma(
    const u16* __restrict__ fa, const u16* __restrict__ wbf,
    const float* __restrict__ ba, const float* __restrict__ bb,
    const float* __restrict__ bc, u16* __restrict__ fT) {
    const int tid = threadIdx.x;
    const int bid = blockIdx.x;
    const int xcd = bid & 7, local = bid >> 3;
    const int mb = xcd * 25 + local / 12;
    const int nbt = local % 12;
    const int nb = nbt & 3;
    const int t = nbt >> 2;
    const float* bias = (t == 0) ? ba : (t == 1) ? bb : bc;

    // A dbuf [2][128][32] @0/@4096; B dbuf @8192/@12288 (u16 units).
    // epilogue uses [0,17408) u16 -> block LDS = 34,816 B.
    __shared__ __align__(16) u16 smem[17408];

    const u16* Ag = fa + (size_t)t * MROWS * NC + (size_t)mb * 128 * NC;
    const u16* Bg = wbf + (size_t)t * NC * NC + (size_t)nb * 128 * NC;

    const int lane = tid & 63;
    const int wave = tid >> 6;
    const int wm = (wave & 1) * 64;
    const int wn = (wave >> 1) * 64;
    const int quad = lane >> 4;
    const int ln16 = lane & 15;

    const int rL = lane >> 2;   // row within a 16-row DMA chunk
    const int csrc = (lane & 3) ^ ((lane >> 2) & 3) ^ ((lane >> 4) & 3);
    // read-side slot offset (u16) for this lane's fragment chunk
    const int qs = (quad ^ (ln16 & 3) ^ ((ln16 >> 2) & 3)) * 8;

    // preload bias and drain: loop vmcnt counts must see only DMA ops
    float bi[4];
#pragma unroll
    for (int j = 0; j < 4; ++j) bi[j] = bias[nb * 128 + wn + j * 16 + ln16];
    asm volatile("s_waitcnt vmcnt(0)" ::: "memory");
    __builtin_amdgcn_sched_barrier(0);

    f4 acc[4][4];
    const f4 zz = {0.f, 0.f, 0.f, 0.f};
#pragma unroll
    for (int i = 0; i < 4; ++i)
#pragma unroll
        for (int j = 0; j < 4; ++j) acc[i][j] = zz;

    // per wave per k-step: 2 A-chunks + 2 B-chunks = 4 DMA (1KB each)
#define STAGE1(buf, ks) do {                                                   \
        int _ko = (ks) * 32 + csrc * 8;                                        \
        _Pragma("unroll")                                                      \
        for (int _i = 0; _i < 2; ++_i) {                                       \
            int _c = wave * 2 + _i;                                            \
            gload16(Ag + (size_t)(16 * _c + rL) * NC + _ko,                    \
                    &smem[(buf) * 4096 + _c * 512]);                           \
            gload16(Bg + (size_t)(16 * _c + rL) * NC + _ko,                    \
                    &smem[8192 + (buf) * 4096 + _c * 512]);                    \
        }                                                                      \
    } while (0)

    STAGE1(0, 0);
    STAGE1(1, 1);
#pragma unroll
    for (int ks = 0; ks < 16; ++ks) {
        if (ks < 15) asm volatile("s_waitcnt vmcnt(4)" ::: "memory");
        else         asm volatile("s_waitcnt vmcnt(0)" ::: "memory");
        __builtin_amdgcn_s_barrier();        // all waves passed their waits
        __builtin_amdgcn_sched_barrier(0);
        {
            const u16* Ab = &smem[(ks & 1) * 4096];
            const u16* Bb = &smem[8192 + (ks & 1) * 4096];
            bh8 afr[4], bfr[4];
#pragma unroll
            for (int s = 0; s < 4; ++s) {
                afr[s] = *(const bh8*)&Ab[(wm + s * 16 + ln16) * 32 + qs];
                bfr[s] = *(const bh8*)&Bb[(wn + s * 16 + ln16) * 32 + qs];
            }
#pragma unroll
            for (int i = 0; i < 4; ++i)
#pragma unroll
                for (int j = 0; j < 4; ++j)
                    acc[i][j] = __builtin_amdgcn_mfma_f32_16x16x32_bf16(
                        afr[i], bfr[j], acc[i][j], 0, 0, 0);
        }
        __builtin_amdgcn_sched_barrier(0);
        __builtin_amdgcn_s_barrier();        // all reads of buf[ks&1] done
        __builtin_amdgcn_sched_barrier(0);
        if (ks < 14) STAGE1(ks & 1, ks + 2);
    }
#undef STAGE1

    // epilogue: bias + bf16 pack into LDS tile [128][136], coalesced stores
    __syncthreads();
#pragma unroll
    for (int j = 0; j < 4; ++j) {
        int tcol = wn + j * 16 + ln16;
#pragma unroll
        for (int i = 0; i < 4; ++i) {
            int trow = wm + i * 16 + quad * 4;
#pragma unroll
            for (int r = 0; r < 4; ++r)
                smem[(trow + r) * 136 + tcol] = f2bf(acc[i][j][r] + bi[j]);
        }
    }
    __syncthreads();
    const size_t obase = ((size_t)t * MROWS + (size_t)mb * 128) * NC + nb * 128;
#pragma unroll
    for (int it = 0; it < 8; ++it) {
        int idx = tid + 256 * it;
        int row = idx >> 4, ck = idx & 15;
        *(uint4*)(fT + obase + (size_t)row * NC + ck * 8) =
            *(const uint4*)&smem[row * 136 + ck * 8];
    }
}

// ---- Gram via MFMA; XCD-aware 1D grid ----
// 1536 blocks; m97-style single-buffer DMA schedule (count-robust).
__global__ __launch_bounds__(256) void k_gram_mfma(const u16* __restrict__ fT,
                                                   u16* __restrict__ corr) {
    const int tid = threadIdx.x;
    const int bid = blockIdx.x;
    const int xcd = bid & 7, local = bid >> 3;
    const int gidx = xcd * 48 + (local >> 2);
    const int mt = local & 3;
    const int b = gidx / 3, pair = gidx % 3;
    const int tA = (pair == 2) ? 1 : 0;
    const int tB = (pair == 0) ? 1 : 2;

    __shared__ __align__(16) u16 smem[20480];   // 40,960 B

    const u16* Ag = fT + ((size_t)tA * NB + b) * NP * NC + (size_t)mt * 64 * NC;
    const u16* Bg = fT + ((size_t)tB * NB + b) * NP * NC;

    const int lane = tid & 63;
    const int wave = tid >> 6;
    const int wn = wave * 64;
    const int quad = lane >> 4;
    const int ln16 = lane & 15;

    const int r0 = lane >> 3;
    const int csrc = (lane & 7) ^ r0;

    f4 acc[4][4];
    const f4 zz = {0.f, 0.f, 0.f, 0.f};
#pragma unroll
    for (int i = 0; i < 4; ++i)
#pragma unroll
        for (int j = 0; j < 4; ++j) acc[i][j] = zz;

#define STAGE2(ks) do {                                                        \
        int _ko = (ks) * 64 + csrc * 8;                                        \
        _Pragma("unroll")                                                      \
        for (int _i = 0; _i < 2; ++_i) {                                       \
            int _ra = wave * 16 + _i * 8;                                      \
            gload16(Ag + (size_t)(_ra + r0) * NC + _ko, &smem[_ra * 64]);      \
        }                                                                      \
        _Pragma("unroll")                                                      \
        for (int _i = 0; _i < 8; ++_i) {                                       \
            int _rb = wave * 64 + _i * 8;                                      \
            gload16(Bg + (size_t)(_rb + r0) * NC + _ko,                        \
                    &smem[4096 + _rb * 64]);                                   \
        }                                                                      \
    } while (0)

#pragma unroll
    for (int ks = 0; ks < 8; ++ks) {
        __syncthreads();
        STAGE2(ks);
        __syncthreads();
#pragma unroll
        for (int h = 0; h < 2; ++h) {
            bh8 afr[4], bfr[4];
#pragma unroll
            for (int s = 0; s < 4; ++s) {
                int cw = ((h * 4 + quad) ^ (ln16 & 7)) * 8;
                afr[s] = *(const bh8*)&smem[(s * 16 + ln16) * 64 + cw];
                bfr[s] = *(const bh8*)&smem[4096 + (wn + s * 16 + ln16) * 64 + cw];
            }
#pragma unroll
            for (int i = 0; i < 4; ++i)
#pragma unroll
                for (int j = 0; j < 4; ++j)
                    acc[i][j] = __builtin_amdgcn_mfma_f32_16x16x32_bf16(
                        afr[i], bfr[j], acc[i][j], 0, 0, 0);
        }
    }
#undef STAGE2

    // epilogue, two 32-row passes: zero 32x448, scatter valid (p1,ch), write
    u16* Crow = corr + ((size_t)(b * 3 + pair)) * NP * NDP;
#pragma unroll
    for (int half = 0; half < 2; ++half) {
        __syncthreads();
        {
            const uint4 z4 = make_uint4(0, 0, 0, 0);
#pragma unroll
            for (int it = 0; it < 14; ++it)          // 32*448 u16 = 3584 uint4
                ((uint4*)smem)[tid + 256 * it] = z4;
        }
        __syncthreads();
#pragma unroll
        for (int i = half * 2; i < half * 2 + 2; ++i) {
#pragma unroll
            for (int r = 0; r < 4; ++r) {
                int p1l = i * 16 + quad * 4 + r;     // in [half*32, half*32+32)
                int lrow = p1l - half * 32;
                int p1 = mt * 64 + p1l;
                if (p1 >= NP) continue;
                int y1 = p1 / 20, x1 = p1 - y1 * 20;
#pragma unroll
                for (int j = 0; j < 4; ++j) {
                    int p2 = wn + j * 16 + ln16;
                    if (p2 >= NP) continue;
                    int y2 = p2 / 20, x2 = p2 - y2 * 20;
                    int oy = y2 - y1, ox = x2 - x1;
                    if (((oy | ox) & 1) == 0) {
                        int ch = ((oy + 20) >> 1) * 21 + ((ox + 20) >> 1);
                        float v = acc[i][j][r] * (1.0f / 512.0f);
                        v = (v > 0.0f) ? v : 0.1f * v;
                        smem[lrow * NDP + ch] = f2bf(v);
                    }
                }
            }
        }
        __syncthreads();
#pragma unroll
        for (int it = 0; it < 7; ++it) {             // 32 rows * 56 uint4
            int idx = tid + 256 * it;
            int row = idx / 56, cq = idx - row * 56;
            int p1 = mt * 64 + half * 32 + row;
            if (p1 < NP)
                *(uint4*)(Crow + (size_t)p1 * NDP + cq * 8) =
                    *(const uint4*)&smem[row * NDP + cq * 8];
        }
    }
}

// ---- both conv-GEMMs in one dispatch: grid (400, 2), y = mode ----
// Barrier-free, LDS-free register-fragment version (N=32 stream GEMM).
__global__ __launch_bounds__(256) void k_convgemm(const u16* __restrict__ corr,
                                                  const u16* __restrict__ fT,
                                                  const u16* __restrict__ wctb,
                                                  const u16* __restrict__ wcatb,
                                                  float* __restrict__ Ucorr,
                                                  float* __restrict__ Ucat) {
    const int tid = threadIdx.x;
    const int mode = blockIdx.y;
    const u16* A0 = mode ? fT : corr;
    const u16* Bn = mode ? wcatb : wctb;
    float* U = mode ? Ucat : Ucorr;
    const int kiters = mode ? (KCAT / 64) : (KCORR / 64);
    const int Kpad = kiters * 64;

    const int lane = tid & 63;
    const int wave = tid >> 6;
    const int quad = lane >> 4;
    const int ln16 = lane & 15;
    const int wbase = (blockIdx.x * 4 + wave) * 16;   // wave's 16 output rows
    const int arow = wbase + ln16;                    // this lane's A row

    size_t abase;
    if (mode == 0) {
        int b = arow / NP, p = arow - b * NP;
        abase = ((size_t)(b * 3) * NP + p) * NDP;
    } else {
        abase = (size_t)arow * NC;
    }

    f4 acc0 = {0, 0, 0, 0}, acc1 = {0, 0, 0, 0};

    bh8 pa[2][2], pb0[2][2], pb1[2][2];   // [buf][h], literal-indexed only

#define PFC(buf, ks) do {                                                      \
        _Pragma("unroll")                                                      \
        for (int _h = 0; _h < 2; ++_h) {                                       \
            int _k = (ks) * 64 + _h * 32 + quad * 8;                           \
            const u16* _ap;                                                    \
            if (mode == 0) {                                                   \
                int _pr = _k / NDP;                                            \
                _ap = A0 + abase + (size_t)_pr * (NP * NDP) + (_k - _pr * NDP);\
            } else {                                                           \
                _ap = A0 + (size_t)(_k >> 9) * ((size_t)MROWS * NC) + abase    \
                      + (_k & 511);                                            \
            }                                                                  \
            pa[buf][_h]  = *(const bh8*)_ap;                                   \
            pb0[buf][_h] = *(const bh8*)(Bn + (size_t)ln16 * Kpad + _k);       \
            pb1[buf][_h] = *(const bh8*)(Bn + (size_t)(16 + ln16) * Kpad + _k);\
        }                                                                      \
    } while (0)

#define CGM(buf) do {                                                          \
        acc0 = __builtin_amdgcn_mfma_f32_16x16x32_bf16(pa[buf][0],             \
                   pb0[buf][0], acc0, 0, 0, 0);                                \
        acc1 = __builtin_amdgcn_mfma_f32_16x16x32_bf16(pa[buf][0],             \
                   pb1[buf][0], acc1, 0, 0, 0);                                \
        acc0 = __builtin_amdgcn_mfma_f32_16x16x32_bf16(pa[buf][1],             \
                   pb0[buf][1], acc0, 0, 0, 0);                                \
        acc1 = __builtin_amdgcn_mfma_f32_16x16x32_bf16(pa[buf][1],             \
                   pb1[buf][1], acc1, 0, 0, 0);                                \
    } while (0)

    PFC(0, 0);
    PFC(1, 1);
    int ks = 0;
    for (; ks + 1 < kiters; ks += 2) {
        CGM(0);
        if (ks + 2 < kiters) PFC(0, ks + 2);
        CGM(1);
        if (ks + 3 < kiters) PFC(1, ks + 3);
    }
    if (ks < kiters) CGM(0);   // odd kiters tail (mode 0: 21 steps)
#undef PFC
#undef CGM

    const int orow = wbase + quad * 4;
#pragma unroll
    for (int r = 0; r < 4; ++r) {
        U[(size_t)(orow + r) * 32 + ln16] = acc0[r];
        U[(size_t)(orow + r) * 32 + 16 + ln16] = acc1[r];
    }
}

// ---- merged tail: 9-neighbor gather + bias/relu + both MLPs + final linear ----
__global__ __launch_bounds__(256) void k_tail(
    const float* __restrict__ Ucorr, const float* __restrict__ Ucat,
    const float* __restrict__ bcorr, const float* __restrict__ bcat,
    const float* __restrict__ cf_w1, const float* __restrict__ cf_b1,
    const float* __restrict__ cf_w2, const float* __restrict__ cf_b2,
    const float* __restrict__ ccf_w1, const float* __restrict__ ccf_b1,
    const float* __restrict__ ccf_w2, const float* __restrict__ ccf_b2,
    const float* __restrict__ Wout, const float* __restrict__ bout,
    float* __restrict__ out) {
    const int tid = threadIdx.x;
    const int b = blockIdx.x;
    __shared__ float Lc[NP][28];
    __shared__ float La[NP][28];
    __shared__ float cv[600], vv[600], h1[256], h2a[128], h2b[128];
    for (int idx = tid; idx < NP * 27; idx += 256) {
        int p = idx / 27, n = idx - p * 27;
        Lc[p][n] = Ucorr[(size_t)(b * NP + p) * 32 + n];
        La[p][n] = Ucat[(size_t)(b * NP + p) * 32 + n];
    }
    __syncthreads();
    for (int idx = tid; idx < 1200; idx += 256) {
        int path = idx / 600;
        int rem = idx - path * 600;
        int o = rem / 200, p = rem - o * 200;
        int y = p / 20, x = p - y * 20;
        float s = (path == 0) ? bcorr[o] : bcat[o];
        for (int ky = 0; ky < 3; ++ky) {
            int yy = y + ky - 1;
            if (yy < 0 || yy >= NH) continue;
            for (int kx = 0; kx < 3; ++kx) {
                int xx = x + kx - 1;
                if (xx < 0 || xx >= NW) continue;
                int n = (ky * 3 + kx) * 3 + o;
                s += (path == 0) ? Lc[yy * 20 + xx][n] : La[yy * 20 + xx][n];
            }
        }
        if (path == 0) cv[rem] = fmaxf(s, 0.0f);
        else           vv[rem] = s;
    }
    __syncthreads();
    {
        float s = cf_b1[tid];
        const float* wr = cf_w1 + (size_t)tid * 600;
        for (int k = 0; k < 600; k += 4) {
            float4 wv = *(const float4*)&wr[k];
            s = fmaf(cv[k], wv.x, s); s = fmaf(cv[k + 1], wv.y, s);
            s = fmaf(cv[k + 2], wv.z, s); s = fmaf(cv[k + 3], wv.w, s);
        }
        h1[tid] = fmaxf(s, 0.0f);
    }
    __syncthreads();
    if (tid < 128) {
        float s = cf_b2[tid];
        const float* wr = cf_w2 + (size_t)tid * 256;
        for (int k = 0; k < 256; k += 4) {
            float4 wv = *(const float4*)&wr[k];
            s = fmaf(h1[k], wv.x, s); s = fmaf(h1[k + 1], wv.y, s);
            s = fmaf(h1[k + 2], wv.z, s); s = fmaf(h1[k + 3], wv.w, s);
        }
        h2a[tid] = fmaxf(s, 0.0f);
    }
    __syncthreads();
    {
        float s = ccf_b1[tid];
        const float* wr = ccf_w1 + (size_t)tid * 600;
        for (int k = 0; k < 600; k += 4) {
            float4 wv = *(const float4*)&wr[k];
            s = fmaf(vv[k], wv.x, s); s = fmaf(vv[k + 1], wv.y, s);
            s = fmaf(vv[k + 2], wv.z, s); s = fmaf(vv[k + 3], wv.w, s);
        }
        h1[tid] = fmaxf(s, 0.0f);
    }
    __syncthreads();
    if (tid < 128) {
        float s = ccf_b2[tid];
        const float* wr = ccf_w2 + (size_t)tid * 256;
        for (int k = 0; k < 256; k += 4) {
            float4 wv = *(const float4*)&wr[k];
            s = fmaf(h1[k], wv.x, s); s = fmaf(h1[k + 1], wv.y, s);
            s = fmaf(h1[k + 2], wv.z, s); s = fmaf(h1[k + 3], wv.w, s);
        }
        h2b[tid] = fmaxf(s, 0.0f);
    }
    __syncthreads();
    if (tid < 2) {
        float s = bout[tid];
        const float* wr = Wout + (size_t)tid * 256;
        for (int k = 0; k < 128; ++k) {
            s = fmaf(h2a[k], wr[k], s);
            s = fmaf(h2b[k], wr[128 + k], s);
        }
        out[(size_t)b * 2 + tid] = s;
    }
}

extern "C" void kernel_launch(void* const* d_in, const int* in_sizes, int n_in,
                              void* d_out, int out_size, void* d_ws, size_t ws_size,
                              hipStream_t stream) {
    const float* feat1  = (const float*)d_in[0];
    const float* feat2  = (const float*)d_in[1];
    const float* feat3  = (const float*)d_in[2];
    const float* Wa     = (const float*)d_in[3];
    const float* ba     = (const float*)d_in[4];
    const float* Wb     = (const float*)d_in[5];
    const float* bb     = (const float*)d_in[6];
    const float* Wc     = (const float*)d_in[7];
    const float* bc     = (const float*)d_in[8];
    const float* Wcorr  = (const float*)d_in[9];
    const float* bcorr  = (const float*)d_in[10];
    const float* Wcat   = (const float*)d_in[11];
    const float* bcat   = (const float*)d_in[12];
    const float* cf_w1  = (const float*)d_in[13];
    const float* cf_b1  = (const float*)d_in[14];
    const float* cf_w2  = (const float*)d_in[15];
    const float* cf_b2  = (const float*)d_in[16];
    const float* ccf_w1 = (const float*)d_in[17];
    const float* ccf_b1 = (const float*)d_in[18];
    const float* ccf_w2 = (const float*)d_in[19];
    const float* ccf_b2 = (const float*)d_in[20];
    const float* Wout   = (const float*)d_in[21];
    const float* bout   = (const float*)d_in[22];

    char* ws = (char*)d_ws;
    u16*  fa    = (u16*)(ws + OFF_FA);
    u16*  corr  = (u16*)(ws + OFF_CORR);     // aliases fa (disjoint lifetimes)
    float* Ucorr = (float*)(ws + OFF_UCORR);  // aliases fa tail
    float* Ucat  = (float*)(ws + OFF_UCAT);
    u16*  fT    = (u16*)(ws + OFF_FT);
    u16*  wbf   = (u16*)(ws + OFF_WBF);
    u16*  wctb  = (u16*)(ws + OFF_WCTB);
    u16*  wcatb = (u16*)(ws + OFF_WCATB);

    k_prep_fa<<<6504, 256, 0, stream>>>(feat1, feat2, feat3, fa,
                                        Wcorr, Wcat, Wa, Wb, Wc,
                                        wctb, wcatb, wbf);
    k_conv1x1_mfma<<<2400, 256, 0, stream>>>(fa, wbf, ba, bb, bc, fT);
    // fa dead from here; gram writes every byte of corr (no memset needed)
    k_gram_mfma<<<1536, 256, 0, stream>>>(fT, corr);
    k_convgemm<<<dim3(400, 2), 256, 0, stream>>>(corr, fT, wctb, wcatb, Ucorr, Ucat);
    k_tail<<<128, 256, 0, stream>>>(Ucorr, Ucat, bcorr, bcat,
                                    cf_w1, cf_b1, cf_w2, cf_b2,
                                    ccf_w1, ccf_b1, ccf_w2, ccf_b2, Wout, bout,
                                    (float*)d_out);
}

// Round 6
// 437.206 us; speedup vs baseline: 1.5905x; 1.0233x over previous
//
#include <hip/hip_runtime.h>
#include <stdint.h>

#define NB 128
#define NC 512
#define NH 10
#define NW 20
#define NP 200      // NH*NW
#define ND3 1323
#define NDP 448     // per-pair padded channel row (441 -> 448, 896B aligned)
#define MROWS 25600 // NB*NP flattened GEMM rows per tensor
#define KCORR 1344  // 3*448 K extent for corr conv-GEMM
#define KCAT  1536  // 3*512

typedef unsigned short u16;
typedef unsigned int u32;

typedef short bh8 __attribute__((ext_vector_type(8)));   // 8 bf16 (4 VGPRs)
typedef float f4 __attribute__((ext_vector_type(4)));    // 4 fp32 acc

// ---- workspace layout (bytes) ----
#define OFF_FA     0ULL
#define SZ_FA      (3ULL*MROWS*NC*2)             // 78,643,200
#define OFF_CORR   0ULL
#define SZ_CORR    (3ULL*NB*NP*NDP*2)            // 68,812,800  [b][pair][p][448]
#define OFF_UCORR  (OFF_CORR + SZ_CORR + 256)
#define SZ_U       (1ULL*MROWS*32*4)             // 3,276,800
#define OFF_UCAT   (OFF_UCORR + SZ_U)            // ends ~75.4MB < 78.6MB
#define OFF_FT     (OFF_FA + SZ_FA)
#define SZ_FT      (3ULL*MROWS*NC*2 + 65536)     // +64 pad rows for over-read
#define OFF_WBF    (OFF_FT + SZ_FT)
#define SZ_WBF     (3ULL*NC*NC*2)
#define OFF_WCTB   (OFF_WBF + SZ_WBF)
#define SZ_WCTB    (32ULL*KCORR*2)               // bf16 [32][1344]
#define OFF_WCATB  (OFF_WCTB + SZ_WCTB)
#define SZ_WCATB   (32ULL*KCAT*2)                // bf16 [32][1536]

__device__ __forceinline__ float bf2f(u16 a) {
    return __uint_as_float(((u32)a) << 16);
}
__device__ __forceinline__ u16 f2bf(float x) {
    u32 u = __float_as_uint(x);
    return (u16)((u + 0x7fffu + ((u >> 16) & 1u)) >> 16);
}

// direct global->LDS DMA, 16B per lane. lds dest must be wave-uniform base;
// HW scatters lane l to base + l*16.
__device__ __forceinline__ void gload16(const void* g, void* l) {
    __builtin_amdgcn_global_load_lds(
        (const __attribute__((address_space(1))) void*)g,
        (__attribute__((address_space(3))) void*)l, 16, 0, 0);
}

// ---- merged prep + transpose: one launch ----
// blocks [0,3072): fa transpose (ct = bid&7, y = bid>>3)
// blocks [3072,6504): bf16 weight prep
// fa load phase: lane (cl,pc) reads float4 at p = u*16 + pc*4 -> per
// instruction the 4 pc-lanes of a row cover one contiguous 64B granule
// (100% line utilization, no L1-retention dependence). Same (p,c) values
// land at the same LDS slots as before -> fa bitwise identical.
__global__ __launch_bounds__(256) void k_prep_fa(
    const float* __restrict__ feat1, const float* __restrict__ feat2,
    const float* __restrict__ feat3, u16* __restrict__ fa,
    const float* __restrict__ Wcorr, const float* __restrict__ Wcat,
    const float* __restrict__ Wa, const float* __restrict__ Wb,
    const float* __restrict__ Wc, u16* __restrict__ wctb,
    u16* __restrict__ wcatb, u16* __restrict__ wbf) {
    const int tid = threadIdx.x;
    const int bid = blockIdx.x;
    if (bid < 3072) {
        const int ct = bid & 7;
        const int yy = bid >> 3;
        const int t = yy >> 7, b = yy & 127;
        const float* feat = (t == 0) ? feat1 : (t == 1) ? feat2 : feat3;

        __shared__ u16 Ls[NP * 72];

        const int cl = tid >> 2;
        const int pc = tid & 3;
        const float* src = feat + ((size_t)b * NC + ct * 64 + cl) * NP;
#pragma unroll
        for (int u = 0; u < 12; ++u) {
            int p = u * 16 + pc * 4;
            float4 v = *(const float4*)(src + p);
            Ls[(p + 0) * 72 + cl] = f2bf(v.x);
            Ls[(p + 1) * 72 + cl] = f2bf(v.y);
            Ls[(p + 2) * 72 + cl] = f2bf(v.z);
            Ls[(p + 3) * 72 + cl] = f2bf(v.w);
        }
        if (pc < 2) {                      // tail p = 192..199
            int p = 192 + pc * 4;
            float4 v = *(const float4*)(src + p);
            Ls[(p + 0) * 72 + cl] = f2bf(v.x);
            Ls[(p + 1) * 72 + cl] = f2bf(v.y);
            Ls[(p + 2) * 72 + cl] = f2bf(v.z);
            Ls[(p + 3) * 72 + cl] = f2bf(v.w);
        }
        __syncthreads();
        for (int idx = tid; idx < 1600; idx += 256) {
            int p = idx >> 3, ck = idx & 7;
            uint4 v = *(const uint4*)&Ls[p * 72 + ck * 8];
            *(uint4*)&fa[((size_t)t * MROWS + b * NP + p) * NC + ct * 64 + ck * 8] = v;
        }
    } else {
        int idx = (bid - 3072) * 256 + tid;
        const int n1 = 32 * KCORR;     // 43008
        const int n2 = 32 * KCAT;      // 49152
        const int n3 = 3 * NC * NC;    // 786432
        if (idx < n1) {
            int k = idx % KCORR;
            int n = idx / KCORR;
            int pair = k / NDP, ch = k - pair * NDP;
            float v = 0.0f;
            if (n < 27 && ch < 441) {
                int d = pair * 441 + ch;
                int tap = n / 3, o = n % 3;
                int ky = tap / 3, kx = tap % 3;
                v = Wcorr[((o * ND3 + d) * 3 + ky) * 3 + kx];
            }
            wctb[idx] = f2bf(v);
        } else if (idx < n1 + n2) {
            int j = idx - n1;
            int i = j % KCAT;
            int n = j / KCAT;
            float v = 0.0f;
            if (n < 27) {
                int tap = n / 3, o = n % 3;
                int ky = tap / 3, kx = tap % 3;
                v = Wcat[((o * 1536 + i) * 3 + ky) * 3 + kx];
            }
            wcatb[j] = f2bf(v);
        } else if (idx < n1 + n2 + n3) {
            int j = idx - n1 - n2;
            int t = j >> 18;
            const float* W = (t == 0) ? Wa : (t == 1) ? Wb : Wc;
            wbf[j] = f2bf(W[j & 262143]);
        }
    }
}

// ---- 1x1 conv as MFMA GEMM, XCD-aware 1D grid ----
// Counted-vmcnt double-buffered DMA pipeline at BK=32 (validated R4):
//   prologue: preload bias + vmcnt(0) drain -> loop VMEM = DMAs only.
//   16 k-steps: vmcnt(4); barrier; ds_read+16 MFMA; barrier; STAGE(ks+2).
__global__ __launch_bounds__(256) void k_conv1x1_mfma(
    const u16* __restrict__ fa, const u16* __restrict__ wbf,
    const float* __restrict__ ba, const float* __restrict__ bb,
    const float* __restrict__ bc, u16* __restrict__ fT) {
    const int tid = threadIdx.x;
    const int bid = blockIdx.x;
    const int xcd = bid & 7, local = bid >> 3;
    const int mb = xcd * 25 + local / 12;
    const int nbt = local % 12;
    const int nb = nbt & 3;
    const int t = nbt >> 2;
    const float* bias = (t == 0) ? ba : (t == 1) ? bb : bc;

    // A dbuf [2][128][32] @0/@4096; B dbuf @8192/@12288 (u16 units).
    // epilogue uses [0,17408) u16 -> block LDS = 34,816 B.
    __shared__ __align__(16) u16 smem[17408];

    const u16* Ag = fa + (size_t)t * MROWS * NC + (size_t)mb * 128 * NC;
    const u16* Bg = wbf + (size_t)t * NC * NC + (size_t)nb * 128 * NC;

    const int lane = tid & 63;
    const int wave = tid >> 6;
    const int wm = (wave & 1) * 64;
    const int wn = (wave >> 1) * 64;
    const int quad = lane >> 4;
    const int ln16 = lane & 15;

    const int rL = lane >> 2;   // row within a 16-row DMA chunk
    const int csrc = (lane & 3) ^ ((lane >> 2) & 3) ^ ((lane >> 4) & 3);
    // read-side slot offset (u16) for this lane's fragment chunk
    const int qs = (quad ^ (ln16 & 3) ^ ((ln16 >> 2) & 3)) * 8;

    // preload bias and drain: loop vmcnt counts must see only DMA ops
    float bi[4];
#pragma unroll
    for (int j = 0; j < 4; ++j) bi[j] = bias[nb * 128 + wn + j * 16 + ln16];
    asm volatile("s_waitcnt vmcnt(0)" ::: "memory");
    __builtin_amdgcn_sched_barrier(0);

    f4 acc[4][4];
    const f4 zz = {0.f, 0.f, 0.f, 0.f};
#pragma unroll
    for (int i = 0; i < 4; ++i)
#pragma unroll
        for (int j = 0; j < 4; ++j) acc[i][j] = zz;

    // per wave per k-step: 2 A-chunks + 2 B-chunks = 4 DMA (1KB each)
#define STAGE1(buf, ks) do {                                                   \
        int _ko = (ks) * 32 + csrc * 8;                                        \
        _Pragma("unroll")                                                      \
        for (int _i = 0; _i < 2; ++_i) {                                       \
            int _c = wave * 2 + _i;                                            \
            gload16(Ag + (size_t)(16 * _c + rL) * NC + _ko,                    \
                    &smem[(buf) * 4096 + _c * 512]);                           \
            gload16(Bg + (size_t)(16 * _c + rL) * NC + _ko,                    \
                    &smem[8192 + (buf) * 4096 + _c * 512]);                    \
        }                                                                      \
    } while (0)

    STAGE1(0, 0);
    STAGE1(1, 1);
#pragma unroll
    for (int ks = 0; ks < 16; ++ks) {
        if (ks < 15) asm volatile("s_waitcnt vmcnt(4)" ::: "memory");
        else         asm volatile("s_waitcnt vmcnt(0)" ::: "memory");
        __builtin_amdgcn_s_barrier();        // all waves passed their waits
        __builtin_amdgcn_sched_barrier(0);
        {
            const u16* Ab = &smem[(ks & 1) * 4096];
            const u16* Bb = &smem[8192 + (ks & 1) * 4096];
            bh8 afr[4], bfr[4];
#pragma unroll
            for (int s = 0; s < 4; ++s) {
                afr[s] = *(const bh8*)&Ab[(wm + s * 16 + ln16) * 32 + qs];
                bfr[s] = *(const bh8*)&Bb[(wn + s * 16 + ln16) * 32 + qs];
            }
#pragma unroll
            for (int i = 0; i < 4; ++i)
#pragma unroll
                for (int j = 0; j < 4; ++j)
                    acc[i][j] = __builtin_amdgcn_mfma_f32_16x16x32_bf16(
                        afr[i], bfr[j], acc[i][j], 0, 0, 0);
        }
        __builtin_amdgcn_sched_barrier(0);
        __builtin_amdgcn_s_barrier();        // all reads of buf[ks&1] done
        __builtin_amdgcn_sched_barrier(0);
        if (ks < 14) STAGE1(ks & 1, ks + 2);
    }
#undef STAGE1

    // epilogue: bias + bf16 pack into LDS tile [128][136], coalesced stores
    __syncthreads();
#pragma unroll
    for (int j = 0; j < 4; ++j) {
        int tcol = wn + j * 16 + ln16;
#pragma unroll
        for (int i = 0; i < 4; ++i) {
            int trow = wm + i * 16 + quad * 4;
#pragma unroll
            for (int r = 0; r < 4; ++r)
                smem[(trow + r) * 136 + tcol] = f2bf(acc[i][j][r] + bi[j]);
        }
    }
    __syncthreads();
    const size_t obase = ((size_t)t * MROWS + (size_t)mb * 128) * NC + nb * 128;
#pragma unroll
    for (int it = 0; it < 8; ++it) {
        int idx = tid + 256 * it;
        int row = idx >> 4, ck = idx & 15;
        *(uint4*)(fT + obase + (size_t)row * NC + ck * 8) =
            *(const uint4*)&smem[row * 136 + ck * 8];
    }
}

// ---- Gram via MFMA; XCD-aware 1D grid ----
// 1536 blocks; counted-vmcnt double-buffered DMA at BK=32 (same validated
// structure as conv1x1). A dbuf [2][64][32] @0/@2048; B dbuf [2][256][32]
// @4096/@12288 -> 40,960 B total (same LDS block as before, occupancy flat).
// 16 k-steps ascending in 32-slices = same accumulation order as the old
// BK=64 x h(2) loop -> bitwise-identical output. Loop VMEM = DMAs only.
// 5 DMA/wave/step -> vmcnt(5) in steady state, vmcnt(0) only on last step.
__global__ __launch_bounds__(256) void k_gram_mfma(const u16* __restrict__ fT,
                                                   u16* __restrict__ corr) {
    const int tid = threadIdx.x;
    const int bid = blockIdx.x;
    const int xcd = bid & 7, local = bid >> 3;
    const int gidx = xcd * 48 + (local >> 2);
    const int mt = local & 3;
    const int b = gidx / 3, pair = gidx % 3;
    const int tA = (pair == 2) ? 1 : 0;
    const int tB = (pair == 0) ? 1 : 2;

    __shared__ __align__(16) u16 smem[20480];   // 40,960 B

    const u16* Ag = fT + ((size_t)tA * NB + b) * NP * NC + (size_t)mt * 64 * NC;
    const u16* Bg = fT + ((size_t)tB * NB + b) * NP * NC;

    const int lane = tid & 63;
    const int wave = tid >> 6;
    const int wn = wave * 64;
    const int quad = lane >> 4;
    const int ln16 = lane & 15;

    const int rL = lane >> 2;
    const int csrc = (lane & 3) ^ ((lane >> 2) & 3) ^ ((lane >> 4) & 3);
    const int qs = (quad ^ (ln16 & 3) ^ ((ln16 >> 2) & 3)) * 8;

    f4 acc[4][4];
    const f4 zz = {0.f, 0.f, 0.f, 0.f};
#pragma unroll
    for (int i = 0; i < 4; ++i)
#pragma unroll
        for (int j = 0; j < 4; ++j) acc[i][j] = zz;

    // per wave per k-step: 1 A-chunk (16 rows) + 4 B-chunks = 5 DMA (1KB each)
#define STAGE2(buf, ks) do {                                                   \
        int _ko = (ks) * 32 + csrc * 8;                                        \
        gload16(Ag + (size_t)(wave * 16 + rL) * NC + _ko,                      \
                &smem[(buf) * 2048 + wave * 512]);                             \
        _Pragma("unroll")                                                      \
        for (int _i = 0; _i < 4; ++_i) {                                       \
            int _rb = wave * 64 + _i * 16;                                     \
            gload16(Bg + (size_t)(_rb + rL) * NC + _ko,                        \
                    &smem[4096 + (buf) * 8192 + _rb * 32]);                    \
        }                                                                      \
    } while (0)

    STAGE2(0, 0);
    STAGE2(1, 1);
#pragma unroll
    for (int ks = 0; ks < 16; ++ks) {
        if (ks < 15) asm volatile("s_waitcnt vmcnt(5)" ::: "memory");
        else         asm volatile("s_waitcnt vmcnt(0)" ::: "memory");
        __builtin_amdgcn_s_barrier();
        __builtin_amdgcn_sched_barrier(0);
        {
            const u16* Ab = &smem[(ks & 1) * 2048];
            const u16* Bb = &smem[4096 + (ks & 1) * 8192];
            bh8 afr[4], bfr[4];
#pragma unroll
            for (int s = 0; s < 4; ++s) {
                afr[s] = *(const bh8*)&Ab[(s * 16 + ln16) * 32 + qs];
                bfr[s] = *(const bh8*)&Bb[(wn + s * 16 + ln16) * 32 + qs];
            }
#pragma unroll
            for (int i = 0; i < 4; ++i)
#pragma unroll
                for (int j = 0; j < 4; ++j)
                    acc[i][j] = __builtin_amdgcn_mfma_f32_16x16x32_bf16(
                        afr[i], bfr[j], acc[i][j], 0, 0, 0);
        }
        __builtin_amdgcn_sched_barrier(0);
        __builtin_amdgcn_s_barrier();
        __builtin_amdgcn_sched_barrier(0);
        if (ks < 14) STAGE2(ks & 1, ks + 2);
    }
#undef STAGE2

    // epilogue, two 32-row passes: zero 32x448, scatter valid (p1,ch), write
    u16* Crow = corr + ((size_t)(b * 3 + pair)) * NP * NDP;
#pragma unroll
    for (int half = 0; half < 2; ++half) {
        __syncthreads();
        {
            const uint4 z4 = make_uint4(0, 0, 0, 0);
#pragma unroll
            for (int it = 0; it < 14; ++it)          // 32*448 u16 = 3584 uint4
                ((uint4*)smem)[tid + 256 * it] = z4;
        }
        __syncthreads();
#pragma unroll
        for (int i = half * 2; i < half * 2 + 2; ++i) {
#pragma unroll
            for (int r = 0; r < 4; ++r) {
                int p1l = i * 16 + quad * 4 + r;     // in [half*32, half*32+32)
                int lrow = p1l - half * 32;
                int p1 = mt * 64 + p1l;
                if (p1 >= NP) continue;
                int y1 = p1 / 20, x1 = p1 - y1 * 20;
#pragma unroll
                for (int j = 0; j < 4; ++j) {
                    int p2 = wn + j * 16 + ln16;
                    if (p2 >= NP) continue;
                    int y2 = p2 / 20, x2 = p2 - y2 * 20;
                    int oy = y2 - y1, ox = x2 - x1;
                    if (((oy | ox) & 1) == 0) {
                        int ch = ((oy + 20) >> 1) * 21 + ((ox + 20) >> 1);
                        float v = acc[i][j][r] * (1.0f / 512.0f);
                        v = (v > 0.0f) ? v : 0.1f * v;
                        smem[lrow * NDP + ch] = f2bf(v);
                    }
                }
            }
        }
        __syncthreads();
#pragma unroll
        for (int it = 0; it < 7; ++it) {             // 32 rows * 56 uint4
            int idx = tid + 256 * it;
            int row = idx / 56, cq = idx - row * 56;
            int p1 = mt * 64 + half * 32 + row;
            if (p1 < NP)
                *(uint4*)(Crow + (size_t)p1 * NDP + cq * 8) =
                    *(const uint4*)&smem[row * NDP + cq * 8];
        }
    }
}

// ---- both conv-GEMMs in one dispatch: grid (400, 2), y = mode ----
// Barrier-free, LDS-free register-fragment version (N=32 stream GEMM).
__global__ __launch_bounds__(256) void k_convgemm(const u16* __restrict__ corr,
                                                  const u16* __restrict__ fT,
                                                  const u16* __restrict__ wctb,
                                                  const u16* __restrict__ wcatb,
                                                  float* __restrict__ Ucorr,
                                                  float* __restrict__ Ucat) {
    const int tid = threadIdx.x;
    const int mode = blockIdx.y;
    const u16* A0 = mode ? fT : corr;
    const u16* Bn = mode ? wcatb : wctb;
    float* U = mode ? Ucat : Ucorr;
    const int kiters = mode ? (KCAT / 64) : (KCORR / 64);
    const int Kpad = kiters * 64;

    const int lane = tid & 63;
    const int wave = tid >> 6;
    const int quad = lane >> 4;
    const int ln16 = lane & 15;
    const int wbase = (blockIdx.x * 4 + wave) * 16;   // wave's 16 output rows
    const int arow = wbase + ln16;                    // this lane's A row

    size_t abase;
    if (mode == 0) {
        int b = arow / NP, p = arow - b * NP;
        abase = ((size_t)(b * 3) * NP + p) * NDP;
    } else {
        abase = (size_t)arow * NC;
    }

    f4 acc0 = {0, 0, 0, 0}, acc1 = {0, 0, 0, 0};

    bh8 pa[2][2], pb0[2][2], pb1[2][2];   // [buf][h], literal-indexed only

#define PFC(buf, ks) do {                                                      \
        _Pragma("unroll")                                                      \
        for (int _h = 0; _h < 2; ++_h) {                                       \
            int _k = (ks) * 64 + _h * 32 + quad * 8;                           \
            const u16* _ap;                                                    \
            if (mode == 0) {                                                   \
                int _pr = _k / NDP;                                            \
                _ap = A0 + abase + (size_t)_pr * (NP * NDP) + (_k - _pr * NDP);\
            } else {                                                           \
                _ap = A0 + (size_t)(_k >> 9) * ((size_t)MROWS * NC) + abase    \
                      + (_k & 511);                                            \
            }                                                                  \
            pa[buf][_h]  = *(const bh8*)_ap;                                   \
            pb0[buf][_h] = *(const bh8*)(Bn + (size_t)ln16 * Kpad + _k);       \
            pb1[buf][_h] = *(const bh8*)(Bn + (size_t)(16 + ln16) * Kpad + _k);\
        }                                                                      \
    } while (0)

#define CGM(buf) do {                                                          \
        acc0 = __builtin_amdgcn_mfma_f32_16x16x32_bf16(pa[buf][0],             \
                   pb0[buf][0], acc0, 0, 0, 0);                                \
        acc1 = __builtin_amdgcn_mfma_f32_16x16x32_bf16(pa[buf][0],             \
                   pb1[buf][0], acc1, 0, 0, 0);                                \
        acc0 = __builtin_amdgcn_mfma_f32_16x16x32_bf16(pa[buf][1],             \
                   pb0[buf][1], acc0, 0, 0, 0);                                \
        acc1 = __builtin_amdgcn_mfma_f32_16x16x32_bf16(pa[buf][1],             \
                   pb1[buf][1], acc1, 0, 0, 0);                                \
    } while (0)

    PFC(0, 0);
    PFC(1, 1);
    int ks = 0;
    for (; ks + 1 < kiters; ks += 2) {
        CGM(0);
        if (ks + 2 < kiters) PFC(0, ks + 2);
        CGM(1);
        if (ks + 3 < kiters) PFC(1, ks + 3);
    }
    if (ks < kiters) CGM(0);   // odd kiters tail (mode 0: 21 steps)
#undef PFC
#undef CGM

    const int orow = wbase + quad * 4;
#pragma unroll
    for (int r = 0; r < 4; ++r) {
        U[(size_t)(orow + r) * 32 + ln16] = acc0[r];
        U[(size_t)(orow + r) * 32 + 16 + ln16] = acc1[r];
    }
}

// ---- merged tail: 9-neighbor gather + bias/relu + both MLPs + final linear ----
__global__ __launch_bounds__(256) void k_tail(
    const float* __restrict__ Ucorr, const float* __restrict__ Ucat,
    const float* __restrict__ bcorr, const float* __restrict__ bcat,
    const float* __restrict__ cf_w1, const float* __restrict__ cf_b1,
    const float* __restrict__ cf_w2, const float* __restrict__ cf_b2,
    const float* __restrict__ ccf_w1, const float* __restrict__ ccf_b1,
    const float* __restrict__ ccf_w2, const float* __restrict__ ccf_b2,
    const float* __restrict__ Wout, const float* __restrict__ bout,
    float* __restrict__ out) {
    const int tid = threadIdx.x;
    const int b = blockIdx.x;
    __shared__ float Lc[NP][28];
    __shared__ float La[NP][28];
    __shared__ float cv[600], vv[600], h1[256], h2a[128], h2b[128];
    for (int idx = tid; idx < NP * 27; idx += 256) {
        int p = idx / 27, n = idx - p * 27;
        Lc[p][n] = Ucorr[(size_t)(b * NP + p) * 32 + n];
        La[p][n] = Ucat[(size_t)(b * NP + p) * 32 + n];
    }
    __syncthreads();
    for (int idx = tid; idx < 1200; idx += 256) {
        int path = idx / 600;
        int rem = idx - path * 600;
        int o = rem / 200, p = rem - o * 200;
        int y = p / 20, x = p - y * 20;
        float s = (path == 0) ? bcorr[o] : bcat[o];
        for (int ky = 0; ky < 3; ++ky) {
            int yy = y + ky - 1;
            if (yy < 0 || yy >= NH) continue;
            for (int kx = 0; kx < 3; ++kx) {
                int xx = x + kx - 1;
                if (xx < 0 || xx >= NW) continue;
                int n = (ky * 3 + kx) * 3 + o;
                s += (path == 0) ? Lc[yy * 20 + xx][n] : La[yy * 20 + xx][n];
            }
        }
        if (path == 0) cv[rem] = fmaxf(s, 0.0f);
        else           vv[rem] = s;
    }
    __syncthreads();
    {
        float s = cf_b1[tid];
        const float* wr = cf_w1 + (size_t)tid * 600;
        for (int k = 0; k < 600; k += 4) {
            float4 wv = *(const float4*)&wr[k];
            s = fmaf(cv[k], wv.x, s); s = fmaf(cv[k + 1], wv.y, s);
            s = fmaf(cv[k + 2], wv.z, s); s = fmaf(cv[k + 3], wv.w, s);
        }
        h1[tid] = fmaxf(s, 0.0f);
    }
    __syncthreads();
    if (tid < 128) {
        float s = cf_b2[tid];
        const float* wr = cf_w2 + (size_t)tid * 256;
        for (int k = 0; k < 256; k += 4) {
            float4 wv = *(const float4*)&wr[k];
            s = fmaf(h1[k], wv.x, s); s = fmaf(h1[k + 1], wv.y, s);
            s = fmaf(h1[k + 2], wv.z, s); s = fmaf(h1[k + 3], wv.w, s);
        }
        h2a[tid] = fmaxf(s, 0.0f);
    }
    __syncthreads();
    {
        float s = ccf_b1[tid];
        const float* wr = ccf_w1 + (size_t)tid * 600;
        for (int k = 0; k < 600; k += 4) {
            float4 wv = *(const float4*)&wr[k];
            s = fmaf(vv[k], wv.x, s); s = fmaf(vv[k + 1], wv.y, s);
            s = fmaf(vv[k + 2], wv.z, s); s = fmaf(vv[k + 3], wv.w, s);
        }
        h1[tid] = fmaxf(s, 0.0f);
    }
    __syncthreads();
    if (tid < 128) {
        float s = ccf_b2[tid];
        const float* wr = ccf_w2 + (size_t)tid * 256;
        for (int k = 0; k < 256; k += 4) {
            float4 wv = *(const float4*)&wr[k];
            s = fmaf(h1[k], wv.x, s); s = fmaf(h1[k + 1], wv.y, s);
            s = fmaf(h1[k + 2], wv.z, s); s = fmaf(h1[k + 3], wv.w, s);
        }
        h2b[tid] = fmaxf(s, 0.0f);
    }
    __syncthreads();
    if (tid < 2) {
        float s = bout[tid];
        const float* wr = Wout + (size_t)tid * 256;
        for (int k = 0; k < 128; ++k) {
            s = fmaf(h2a[k], wr[k], s);
            s = fmaf(h2b[k], wr[128 + k], s);
        }
        out[(size_t)b * 2 + tid] = s;
    }
}

extern "C" void kernel_launch(void* const* d_in, const int* in_sizes, int n_in,
                              void* d_out, int out_size, void* d_ws, size_t ws_size,
                              hipStream_t stream) {
    const float* feat1  = (const float*)d_in[0];
    const float* feat2  = (const float*)d_in[1];
    const float* feat3  = (const float*)d_in[2];
    const float* Wa     = (const float*)d_in[3];
    const float* ba     = (const float*)d_in[4];
    const float* Wb     = (const float*)d_in[5];
    const float* bb     = (const float*)d_in[6];
    const float* Wc     = (const float*)d_in[7];
    const float* bc     = (const float*)d_in[8];
    const float* Wcorr  = (const float*)d_in[9];
    const float* bcorr  = (const float*)d_in[10];
    const float* Wcat   = (const float*)d_in[11];
    const float* bcat   = (const float*)d_in[12];
    const float* cf_w1  = (const float*)d_in[13];
    const float* cf_b1  = (const float*)d_in[14];
    const float* cf_w2  = (const float*)d_in[15];
    const float* cf_b2  = (const float*)d_in[16];
    const float* ccf_w1 = (const float*)d_in[17];
    const float* ccf_b1 = (const float*)d_in[18];
    const float* ccf_w2 = (const float*)d_in[19];
    const float* ccf_b2 = (const float*)d_in[20];
    const float* Wout   = (const float*)d_in[21];
    const float* bout   = (const float*)d_in[22];

    char* ws = (char*)d_ws;
    u16*  fa    = (u16*)(ws + OFF_FA);
    u16*  corr  = (u16*)(ws + OFF_CORR);     // aliases fa (disjoint lifetimes)
    float* Ucorr = (float*)(ws + OFF_UCORR);  // aliases fa tail
    float* Ucat  = (float*)(ws + OFF_UCAT);
    u16*  fT    = (u16*)(ws + OFF_FT);
    u16*  wbf   = (u16*)(ws + OFF_WBF);
    u16*  wctb  = (u16*)(ws + OFF_WCTB);
    u16*  wcatb = (u16*)(ws + OFF_WCATB);

    k_prep_fa<<<6504, 256, 0, stream>>>(feat1, feat2, feat3, fa,
                                        Wcorr, Wcat, Wa, Wb, Wc,
                                        wctb, wcatb, wbf);
    k_conv1x1_mfma<<<2400, 256, 0, stream>>>(fa, wbf, ba, bb, bc, fT);
    // fa dead from here; gram writes every byte of corr (no memset needed)
    k_gram_mfma<<<1536, 256, 0, stream>>>(fT, corr);
    k_convgemm<<<dim3(400, 2), 256, 0, stream>>>(corr, fT, wctb, wcatb, Ucorr, Ucat);
    k_tail<<<128, 256, 0, stream>>>(Ucorr, Ucat, bcorr, bcat,
                                    cf_w1, cf_b1, cf_w2, cf_b2,
                                    ccf_w1, ccf_b1, ccf_w2, ccf_b2, Wout, bout,
                                    (float*)d_out);
}